// Round 4
// baseline (9976.331 us; speedup 1.0000x reference)
//
#include <hip/hip_runtime.h>
#include <hip/hip_bf16.h>
#include <hip/hip_fp16.h>

// ---------------------------------------------------------------------------
// MPSGNN: 4 metapath SAGE GNNs + metapath attention + MLP head.
// N_A=40000, N_B=80000, C=256, M=4, E=250000, heads=4 (d=64)
// Round 4: identical to rounds 2/3 (two GPU-acquisition timeouts; no data).
// fp32 compute, fp16 storage for big intermediates, 247MB workspace
// with a runtime ws_size gate + diagnostic fallback.
// ---------------------------------------------------------------------------

#define N_A 40000
#define N_B 80000
#define CDIM 256
#define MP 4
#define EDG 250000

// ---- dtype helpers --------------------------------------------------------
__device__ __forceinline__ float ldf(const float* p) { return *p; }
__device__ __forceinline__ float ldf(const __half* p) { return __half2float(*p); }
__device__ __forceinline__ void stf(float* p, float v) { *p = v; }
__device__ __forceinline__ void stf(__half* p, float v) { *p = __float2half(v); }

__device__ __forceinline__ float4 ld4(const float* p) { return *(const float4*)p; }
__device__ __forceinline__ float4 ld4(const __half* p) {
    __half2 a = *(const __half2*)p, b = *(const __half2*)(p + 2);
    float2 fa = __half22float2(a), fb = __half22float2(b);
    return make_float4(fa.x, fa.y, fb.x, fb.y);
}

// ---------------- GEMM: C[r,c] = op(A[MxK] @ B[KxN]) -----------------------
// 64x64 tile, BK=16, 256 threads (16x16), 4x4 per thread.
// EXTRA_MODE: 0 none, 1 += extra[r,c], 2 += extra[r,c]/max(cnt[r],1)
// AROWSCALE : A[r,k] *= 1/max(cnt[r],1) on load (mean aggregation)
template<typename AT, typename CT, int EXTRA_MODE, bool AROWSCALE, bool BIAS,
         bool RELU, bool OSCALE>
__global__ __launch_bounds__(256) void gemm_k(
    const AT* __restrict__ A, int lda,
    const float* __restrict__ B, int ldb,
    const float* __restrict__ bias,
    const float* __restrict__ extra, int lde,
    const float* __restrict__ cntv,
    const float* __restrict__ oscale_ptr, int oscale_idx,
    CT* __restrict__ C, int ldc,
    int K)
{
    __shared__ float As[16 * 68];   // [k][row], stride 68 -> conflict-free
    __shared__ float Bs[16 * 64];   // [k][col]
    const int tid = threadIdx.x;
    const int tx = tid & 15, ty = tid >> 4;
    const int row0 = blockIdx.y * 64, col0 = blockIdx.x * 64;
    float acc[4][4] = {};
    for (int k0 = 0; k0 < K; k0 += 16) {
        #pragma unroll
        for (int i = 0; i < 4; ++i) {
            int flat = tid + i * 256;
            int r = flat >> 4, kk = flat & 15;
            float v = ldf(&A[(long long)(row0 + r) * lda + (k0 + kk)]);
            if (AROWSCALE) v *= 1.0f / fmaxf(cntv[row0 + r], 1.0f);
            As[kk * 68 + r] = v;
            int kk2 = flat >> 6, c2 = flat & 63;
            Bs[kk2 * 64 + c2] = B[(long long)(k0 + kk2) * ldb + (col0 + c2)];
        }
        __syncthreads();
        #pragma unroll
        for (int kk = 0; kk < 16; ++kk) {
            const float4 a4 = *(const float4*)&As[kk * 68 + ty * 4];
            const float4 b4 = *(const float4*)&Bs[kk * 64 + tx * 4];
            const float av[4] = {a4.x, a4.y, a4.z, a4.w};
            const float bv[4] = {b4.x, b4.y, b4.z, b4.w};
            #pragma unroll
            for (int i = 0; i < 4; ++i)
                #pragma unroll
                for (int j = 0; j < 4; ++j)
                    acc[i][j] = fmaf(av[i], bv[j], acc[i][j]);
        }
        __syncthreads();
    }
    float osc = 1.0f;
    if (OSCALE) osc = oscale_ptr[oscale_idx];
    #pragma unroll
    for (int i = 0; i < 4; ++i) {
        int r = row0 + ty * 4 + i;
        float rs = 1.0f;
        if (EXTRA_MODE == 2) rs = 1.0f / fmaxf(cntv[r], 1.0f);
        #pragma unroll
        for (int j = 0; j < 4; ++j) {
            int c = col0 + tx * 4 + j;
            float v = acc[i][j];
            if (EXTRA_MODE == 1) v += extra[(long long)r * lde + c];
            if (EXTRA_MODE == 2) v += extra[(long long)r * lde + c] * rs;
            if (BIAS) v += bias[c];
            if (RELU) v = fmaxf(v, 0.0f);
            if (OSCALE) v *= osc;
            stf(&C[(long long)r * ldc + c], v);
        }
    }
}

// ---------------- scatter: acc[dst] += feat[src], cnt[dst] += 1 ------------
template<typename FT>
__global__ __launch_bounds__(256) void scatter_k(
    const FT* __restrict__ feat,
    const int* __restrict__ src, const int* __restrict__ dst,
    float* __restrict__ acc, float* __restrict__ cnt, int E)
{
    int t = blockIdx.x * 256 + threadIdx.x;
    int e = t >> 6, lane = t & 63;
    if (e >= E) return;
    int s = src[e], d = dst[e];
    const float4 v = ld4(&feat[(long long)s * CDIM + lane * 4]);
    float* dp = &acc[(long long)d * CDIM + lane * 4];
    atomicAdd(dp + 0, v.x);
    atomicAdd(dp + 1, v.y);
    atomicAdd(dp + 2, v.z);
    atomicAdd(dp + 3, v.w);
    if (lane == 0) atomicAdd(&cnt[d], 1.0f);
}

// ---------------- transpose (tiny, for W.T GEMMs) --------------------------
__global__ void transpose_k(const float* __restrict__ in, float* __restrict__ out,
                            int R, int Cc)
{
    int t = blockIdx.x * 256 + threadIdx.x;
    if (t < R * Cc) {
        int r = t / Cc, c = t % Cc;
        out[(long long)c * R + r] = in[(long long)r * Cc + c];
    }
}

// ---------------- fused per-node attention + mean pool ---------------------
// qkv rows: [node*4 + m][768] (q|k|v). One wave per node.
// pooled[c] = sum_km (0.25*sum_qm attn[h(c),qm,km]) * v[km][c]
__global__ __launch_bounds__(256) void attn_pool_k(
    const float* __restrict__ qkv, float* __restrict__ pooled, int nNodes)
{
    __shared__ float sh[4][3072];
    __shared__ float sW[4][16];
    const int tid = threadIdx.x;
    const int wid = tid >> 6, lane = tid & 63;
    const int node = blockIdx.x * 4 + wid;   // nNodes % 4 == 0: never OOB
    float* S = sh[wid];
    const float* base = qkv + (long long)node * 4 * 768;
    #pragma unroll
    for (int it = 0; it < 12; ++it) {
        int f = lane + it * 64;
        *(float4*)&S[f * 4] = *(const float4*)&base[f * 4];
    }
    __syncthreads();
    const int h = lane >> 4, qm = (lane >> 2) & 3, km = lane & 3;
    const float* qrow = &S[qm * 768 + h * 64];
    const float* krow = &S[km * 768 + 256 + h * 64];
    float s = 0.0f;
    #pragma unroll
    for (int i = 0; i < 64; ++i) s = fmaf(qrow[i], krow[i], s);
    s *= 0.125f;  // 1/sqrt(64)
    float mx = fmaxf(s, __shfl_xor(s, 1));
    mx = fmaxf(mx, __shfl_xor(mx, 2));
    float e = __expf(s - mx);
    float sum = e + __shfl_xor(e, 1);
    sum += __shfl_xor(sum, 2);
    float a = e / sum;
    float tt = a + __shfl_xor(a, 4);
    tt += __shfl_xor(tt, 8);
    if (qm == 0) sW[wid][h * 4 + km] = 0.25f * tt;
    __syncthreads();
    #pragma unroll
    for (int j = 0; j < 4; ++j) {
        int c = j * 64 + lane;
        float p = 0.0f;
        #pragma unroll
        for (int kk = 0; kk < 4; ++kk)
            p = fmaf(sW[wid][j * 4 + kk], S[kk * 768 + 512 + c], p);
        pooled[(long long)node * 256 + c] = p;
    }
}

// ---------------- final: out[n] = h[n] . mlp2_w + mlp2_b -------------------
__global__ __launch_bounds__(256) void mlp2_k(
    const float* __restrict__ h, const float* __restrict__ w,
    const float* __restrict__ b, float* __restrict__ out, int n)
{
    int t = blockIdx.x * 256 + threadIdx.x;
    int node = t >> 6, lane = t & 63;
    if (node >= n) return;
    const float4 hv = *(const float4*)&h[(long long)node * CDIM + lane * 4];
    const float4 wv = *(const float4*)&w[lane * 4];
    float s = hv.x * wv.x + hv.y * wv.y + hv.z * wv.z + hv.w * wv.w;
    #pragma unroll
    for (int off = 1; off < 64; off <<= 1) s += __shfl_xor(s, off);
    if (lane == 0) out[node] = s + b[0];
}

// ---------------- diagnostic fallback --------------------------------------
__global__ void diag_k(float* out, int n, float val)
{
    int t = blockIdx.x * 256 + threadIdx.x;
    if (t < n) out[t] = val;
}

// ---------------------------------------------------------------------------
extern "C" void kernel_launch(void* const* d_in, const int* in_sizes, int n_in,
                              void* d_out, int out_size, void* d_ws, size_t ws_size,
                              hipStream_t stream)
{
    const float* x_a  = (const float*)d_in[0];
    const float* x_b  = (const float*)d_in[1];
    const int*   e_ab = (const int*)d_in[2];
    const int*   e_ba = (const int*)d_in[3];
    const float* wl1  = (const float*)d_in[4];
    const float* wr1  = (const float*)d_in[5];
    const float* b1   = (const float*)d_in[6];
    const float* wl2  = (const float*)d_in[7];
    const float* wr2  = (const float*)d_in[8];
    const float* b2   = (const float*)d_in[9];
    const float* outw = (const float*)d_in[10];
    const float* outb = (const float*)d_in[11];
    const float* mpw  = (const float*)d_in[12];
    const float* ipw  = (const float*)d_in[13];  // [768,256]
    const float* ipb  = (const float*)d_in[14];  // [768]
    const float* aow  = (const float*)d_in[15];  // [256,256]
    const float* aob  = (const float*)d_in[16];
    const float* m1w  = (const float*)d_in[17];
    const float* m1b  = (const float*)d_in[18];
    const float* m2w  = (const float*)d_in[19];
    const float* m2b  = (const float*)d_in[20];
    float* out = (float*)d_out;

    // ---- workspace layout (bytes) ----
    // ZREG  : fp32 [N_A,256]                         40,960,000
    // ACCBR : fp32 [N_B,256]+cntB                    82,240,000
    //   overlays: ACC_A[N_A,256]+cntA (41.1MB) | QKVC (49.2MB) | TMLP (41MB)
    // HBREG : fp16 [N_B,256]                         40,960,000
    //   overlay (phase2): TPROJ fp32 [N_A,256] (exactly 40,960,000 B)
    // EMBS  : fp16 [N_A,4,256]                       81,920,000
    // WT1   : fp32 [256,768]                            786,432
    // WT2   : fp32 [256,256]                            262,144
    const size_t SZ_ZREG = 40960000, SZ_ACCB = 82240000, SZ_HB = 40960000,
                 SZ_EMBS = 81920000, SZ_WT1 = 786432, SZ_WT2 = 262144;
    const size_t NEED = SZ_ZREG + SZ_ACCB + SZ_HB + SZ_EMBS + SZ_WT1 + SZ_WT2;

    if (ws_size < NEED || n_in < 21 || out_size != N_A) {
        // Clean, informative failure: absmax error reported by the harness
        // will equal ws_MB*100 + n_in.
        float diag = (float)((ws_size / (1024ull * 1024ull)) * 100ull + (size_t)n_in);
        diag_k<<<(out_size + 255) / 256, 256, 0, stream>>>(out, out_size, diag);
        return;
    }

    char* base = (char*)d_ws;
    float*  ZREG = (float*)base;
    float*  ACCB = (float*)(base + SZ_ZREG);
    float*  CNTB = (float*)(base + SZ_ZREG + 81920000);
    __half* HBH  = (__half*)(base + SZ_ZREG + SZ_ACCB);
    float*  HBF  = (float*)(base + SZ_ZREG + SZ_ACCB);
    __half* EMBS = (__half*)(base + SZ_ZREG + SZ_ACCB + SZ_HB);
    float*  WT1  = (float*)(base + SZ_ZREG + SZ_ACCB + SZ_HB + SZ_EMBS);
    float*  WT2  = (float*)(base + SZ_ZREG + SZ_ACCB + SZ_HB + SZ_EMBS + SZ_WT1);
    // overlays
    float* ACCA = ACCB;
    float* CNTA = (float*)((char*)ACCB + 40960000);
    float* QKVC = ACCB;
    float* TMLP = ACCB;
    float* T1   = ZREG;
    float* HA   = ZREG;
    float* POOL = ZREG;
    float* TPROJ = HBF;

    transpose_k<<<(768 * 256 + 255) / 256, 256, 0, stream>>>(ipw, WT1, 768, 256);
    transpose_k<<<(256 * 256 + 255) / 256, 256, 0, stream>>>(aow, WT2, 256, 256);

    for (int m = 0; m < MP; ++m) {
        const size_t wo = (size_t)m * CDIM * CDIM;
        const int* sab = e_ab + (size_t)m * 2 * EDG;
        const int* dab = sab + EDG;
        const int* sba = e_ba + (size_t)m * 2 * EDG;
        const int* dba = sba + EDG;

        // z = x_a @ wl1[m]  (pre-transform; linearity of segment mean)
        gemm_k<float, float, 0, false, false, false, false>
            <<<dim3(4, N_A / 64), 256, 0, stream>>>(
            x_a, CDIM, wl1 + wo, CDIM, nullptr, nullptr, 0, nullptr, nullptr, 0,
            ZREG, CDIM, CDIM);
        hipMemsetAsync(ACCB, 0, ((size_t)N_B * 256 + N_B) * 4, stream);
        scatter_k<float><<<(EDG * 64) / 256, 256, 0, stream>>>(
            ZREG, sab, dab, ACCB, CNTB, EDG);
        // h_b = relu(x_b @ wr1[m] + b1[m] + acc_b/max(cnt,1))  -> fp16
        gemm_k<float, __half, 2, false, true, true, false>
            <<<dim3(4, N_B / 64), 256, 0, stream>>>(
            x_b, CDIM, wr1 + wo, CDIM, b1 + (size_t)m * CDIM, ACCB, CDIM, CNTB,
            nullptr, 0, HBH, CDIM, CDIM);
        hipMemsetAsync(ACCA, 0, ((size_t)N_A * 256 + N_A) * 4, stream);
        scatter_k<__half><<<(EDG * 64) / 256, 256, 0, stream>>>(
            HBH, sba, dba, ACCA, CNTA, EDG);
        // t1 = mean_a @ wl2[m]
        gemm_k<float, float, 0, true, false, false, false>
            <<<dim3(4, N_A / 64), 256, 0, stream>>>(
            ACCA, CDIM, wl2 + wo, CDIM, nullptr, nullptr, 0, CNTA, nullptr, 0,
            T1, CDIM, CDIM);
        // h_a = relu(x_a @ wr2[m] + b2[m] + t1)   (C aliases extra: safe, 1:1)
        gemm_k<float, float, 1, false, true, true, false>
            <<<dim3(4, N_A / 64), 256, 0, stream>>>(
            x_a, CDIM, wr2 + wo, CDIM, b2 + (size_t)m * CDIM, T1, CDIM, nullptr,
            nullptr, 0, HA, CDIM, CDIM);
        // embs[:,m,:] = (h_a @ outw[m] + outb[m]) * mp_weights[m]  -> fp16
        gemm_k<float, __half, 0, false, true, false, true>
            <<<dim3(4, N_A / 64), 256, 0, stream>>>(
            HA, CDIM, outw + wo, CDIM, outb + (size_t)m * CDIM, nullptr, 0,
            nullptr, mpw, m, EMBS + (size_t)m * CDIM, 1024, CDIM);
    }

    // phase 2: chunked qkv + fused attention/pool
    const int CH = 4000;  // nodes per chunk -> 16000 rows (divisible by 64)
    for (int ch = 0; ch < N_A / CH; ++ch) {
        const int n0 = ch * CH;
        gemm_k<__half, float, 0, false, true, false, false>
            <<<dim3(12, (CH * 4) / 64), 256, 0, stream>>>(
            EMBS + (size_t)n0 * 1024, CDIM, WT1, 768, ipb, nullptr, 0, nullptr,
            nullptr, 0, QKVC, 768, CDIM);
        attn_pool_k<<<CH / 4, 256, 0, stream>>>(QKVC, POOL + (size_t)n0 * 256, CH);
    }
    // tproj = pooled @ attn_out_w.T + aob   (POOL=ZREG -> TPROJ=HB region)
    gemm_k<float, float, 0, false, true, false, false>
        <<<dim3(4, N_A / 64), 256, 0, stream>>>(
        POOL, CDIM, WT2, CDIM, aob, nullptr, 0, nullptr, nullptr, 0,
        TPROJ, CDIM, CDIM);
    // tmlp = relu(tproj @ mlp1_w + m1b)     (-> ACCB region, QKVC dead)
    gemm_k<float, float, 0, false, true, true, false>
        <<<dim3(4, N_A / 64), 256, 0, stream>>>(
        TPROJ, CDIM, m1w, CDIM, m1b, nullptr, 0, nullptr, nullptr, 0,
        TMLP, CDIM, CDIM);
    mlp2_k<<<(N_A * 64) / 256, 256, 0, stream>>>(TMLP, m2w, m2b, out, N_A);
}

// Round 6
// 4619.979 us; speedup vs baseline: 2.1594x; 2.1594x over previous
//
#include <hip/hip_runtime.h>
#include <hip/hip_bf16.h>
#include <hip/hip_fp16.h>

// ---------------------------------------------------------------------------
// MPSGNN: 4 metapath SAGE GNNs + metapath attention + MLP head.
// N_A=40000, N_B=80000, C=256, M=4, E=250000, heads=4 (d=64)
// Round 6: identical to round 5 (GPU acquisition timeout; no data).
// Replace atomic scatter (850us x8 = 68% of runtime, 4x write amplification
// at the coherence point) with per-call CSR build + gather-mean
// (deterministic, no fp32 atomics). CSR scratch overlays dead regions.
// ---------------------------------------------------------------------------

#define N_A 40000
#define N_B 80000
#define CDIM 256
#define MP 4
#define EDG 250000

// ---- dtype helpers --------------------------------------------------------
__device__ __forceinline__ float ldf(const float* p) { return *p; }
__device__ __forceinline__ float ldf(const __half* p) { return __half2float(*p); }
__device__ __forceinline__ void stf(float* p, float v) { *p = v; }
__device__ __forceinline__ void stf(__half* p, float v) { *p = __float2half(v); }

__device__ __forceinline__ float4 ld4(const float* p) { return *(const float4*)p; }
__device__ __forceinline__ float4 ld4(const __half* p) {
    __half2 a = *(const __half2*)p, b = *(const __half2*)(p + 2);
    float2 fa = __half22float2(a), fb = __half22float2(b);
    return make_float4(fa.x, fa.y, fb.x, fb.y);
}

// ---------------- GEMM: C[r,c] = op(A[MxK] @ B[KxN]) -----------------------
// 64x64 tile, BK=16, 256 threads (16x16), 4x4 per thread.
// EXTRA_MODE: 0 none, 1 += extra[r,c]
template<typename AT, typename CT, int EXTRA_MODE, bool BIAS, bool RELU, bool OSCALE>
__global__ __launch_bounds__(256) void gemm_k(
    const AT* __restrict__ A, int lda,
    const float* __restrict__ B, int ldb,
    const float* __restrict__ bias,
    const float* __restrict__ extra, int lde,
    const float* __restrict__ oscale_ptr, int oscale_idx,
    CT* __restrict__ C, int ldc,
    int K)
{
    __shared__ float As[16 * 68];   // [k][row], stride 68 -> conflict-free
    __shared__ float Bs[16 * 64];   // [k][col]
    const int tid = threadIdx.x;
    const int tx = tid & 15, ty = tid >> 4;
    const int row0 = blockIdx.y * 64, col0 = blockIdx.x * 64;
    float acc[4][4] = {};
    for (int k0 = 0; k0 < K; k0 += 16) {
        #pragma unroll
        for (int i = 0; i < 4; ++i) {
            int flat = tid + i * 256;
            int r = flat >> 4, kk = flat & 15;
            As[kk * 68 + r] = ldf(&A[(long long)(row0 + r) * lda + (k0 + kk)]);
            int kk2 = flat >> 6, c2 = flat & 63;
            Bs[kk2 * 64 + c2] = B[(long long)(k0 + kk2) * ldb + (col0 + c2)];
        }
        __syncthreads();
        #pragma unroll
        for (int kk = 0; kk < 16; ++kk) {
            const float4 a4 = *(const float4*)&As[kk * 68 + ty * 4];
            const float4 b4 = *(const float4*)&Bs[kk * 64 + tx * 4];
            const float av[4] = {a4.x, a4.y, a4.z, a4.w};
            const float bv[4] = {b4.x, b4.y, b4.z, b4.w};
            #pragma unroll
            for (int i = 0; i < 4; ++i)
                #pragma unroll
                for (int j = 0; j < 4; ++j)
                    acc[i][j] = fmaf(av[i], bv[j], acc[i][j]);
        }
        __syncthreads();
    }
    float osc = 1.0f;
    if (OSCALE) osc = oscale_ptr[oscale_idx];
    #pragma unroll
    for (int i = 0; i < 4; ++i) {
        int r = row0 + ty * 4 + i;
        #pragma unroll
        for (int j = 0; j < 4; ++j) {
            int c = col0 + tx * 4 + j;
            float v = acc[i][j];
            if (EXTRA_MODE == 1) v += extra[(long long)r * lde + c];
            if (BIAS) v += bias[c];
            if (RELU) v = fmaxf(v, 0.0f);
            if (OSCALE) v *= osc;
            stf(&C[(long long)r * ldc + c], v);
        }
    }
}

// ---------------- CSR build: hist -> scan -> fill --------------------------
__global__ __launch_bounds__(256) void hist_k(
    const int* __restrict__ dst, int* __restrict__ cnt, int E)
{
    int e = blockIdx.x * 256 + threadIdx.x;
    if (e < E) atomicAdd(&cnt[dst[e]], 1);
}

// one-block exclusive scan of cnt[n] -> start[n] and cursor[n]
__global__ __launch_bounds__(1024) void scan_k(
    const int* __restrict__ cnt, int* __restrict__ start,
    int* __restrict__ cursor, int n)
{
    __shared__ int part[1024];
    const int t = threadIdx.x;
    const int chunk = (n + 1023) >> 10;
    const int lo = t * chunk, hi = min(lo + chunk, n);
    int s = 0;
    for (int i = lo; i < hi; ++i) s += cnt[i];
    part[t] = s;
    __syncthreads();
    for (int off = 1; off < 1024; off <<= 1) {
        int v = (t >= off) ? part[t - off] : 0;
        __syncthreads();
        part[t] += v;
        __syncthreads();
    }
    int base = (t == 0) ? 0 : part[t - 1];
    for (int i = lo; i < hi; ++i) {
        start[i] = base;
        cursor[i] = base;
        base += cnt[i];
    }
}

__global__ __launch_bounds__(256) void fill_k(
    const int* __restrict__ src, const int* __restrict__ dst,
    int* __restrict__ cursor, int* __restrict__ eidx, int E)
{
    int e = blockIdx.x * 256 + threadIdx.x;
    if (e < E) {
        int p = atomicAdd(&cursor[dst[e]], 1);
        eidx[p] = src[e];
    }
}

// ---------------- gather-mean: mean[r] = avg_{e in CSR[r]} feat[src_e] -----
template<typename FT>
__global__ __launch_bounds__(256) void gather_mean_k(
    const FT* __restrict__ feat, const int* __restrict__ start,
    const int* __restrict__ cnt, const int* __restrict__ eidx,
    float* __restrict__ mean, int n)
{
    int t = blockIdx.x * 256 + threadIdx.x;
    int r = t >> 6, lane = t & 63;
    if (r >= n) return;
    const int s0 = start[r], deg = cnt[r];
    float4 acc = make_float4(0.f, 0.f, 0.f, 0.f);
    for (int i = 0; i < deg; ++i) {
        int s = eidx[s0 + i];
        float4 v = ld4(&feat[(long long)s * CDIM + lane * 4]);
        acc.x += v.x; acc.y += v.y; acc.z += v.z; acc.w += v.w;
    }
    const float inv = 1.0f / fmaxf((float)deg, 1.0f);
    acc.x *= inv; acc.y *= inv; acc.z *= inv; acc.w *= inv;
    *(float4*)&mean[(long long)r * CDIM + lane * 4] = acc;
}

// ---------------- transpose (tiny, for W.T GEMMs) --------------------------
__global__ void transpose_k(const float* __restrict__ in, float* __restrict__ out,
                            int R, int Cc)
{
    int t = blockIdx.x * 256 + threadIdx.x;
    if (t < R * Cc) {
        int r = t / Cc, c = t % Cc;
        out[(long long)c * R + r] = in[(long long)r * Cc + c];
    }
}

// ---------------- fused per-node attention + mean pool ---------------------
__global__ __launch_bounds__(256) void attn_pool_k(
    const float* __restrict__ qkv, float* __restrict__ pooled, int nNodes)
{
    __shared__ float sh[4][3072];
    __shared__ float sW[4][16];
    const int tid = threadIdx.x;
    const int wid = tid >> 6, lane = tid & 63;
    const int node = blockIdx.x * 4 + wid;   // nNodes % 4 == 0: never OOB
    float* S = sh[wid];
    const float* base = qkv + (long long)node * 4 * 768;
    #pragma unroll
    for (int it = 0; it < 12; ++it) {
        int f = lane + it * 64;
        *(float4*)&S[f * 4] = *(const float4*)&base[f * 4];
    }
    __syncthreads();
    const int h = lane >> 4, qm = (lane >> 2) & 3, km = lane & 3;
    const float* qrow = &S[qm * 768 + h * 64];
    const float* krow = &S[km * 768 + 256 + h * 64];
    float s = 0.0f;
    #pragma unroll
    for (int i = 0; i < 64; ++i) s = fmaf(qrow[i], krow[i], s);
    s *= 0.125f;  // 1/sqrt(64)
    float mx = fmaxf(s, __shfl_xor(s, 1));
    mx = fmaxf(mx, __shfl_xor(mx, 2));
    float e = __expf(s - mx);
    float sum = e + __shfl_xor(e, 1);
    sum += __shfl_xor(sum, 2);
    float a = e / sum;
    float tt = a + __shfl_xor(a, 4);
    tt += __shfl_xor(tt, 8);
    if (qm == 0) sW[wid][h * 4 + km] = 0.25f * tt;
    __syncthreads();
    #pragma unroll
    for (int j = 0; j < 4; ++j) {
        int c = j * 64 + lane;
        float p = 0.0f;
        #pragma unroll
        for (int kk = 0; kk < 4; ++kk)
            p = fmaf(sW[wid][j * 4 + kk], S[kk * 768 + 512 + c], p);
        pooled[(long long)node * 256 + c] = p;
    }
}

// ---------------- final: out[n] = h[n] . mlp2_w + mlp2_b -------------------
__global__ __launch_bounds__(256) void mlp2_k(
    const float* __restrict__ h, const float* __restrict__ w,
    const float* __restrict__ b, float* __restrict__ out, int n)
{
    int t = blockIdx.x * 256 + threadIdx.x;
    int node = t >> 6, lane = t & 63;
    if (node >= n) return;
    const float4 hv = *(const float4*)&h[(long long)node * CDIM + lane * 4];
    const float4 wv = *(const float4*)&w[lane * 4];
    float s = hv.x * wv.x + hv.y * wv.y + hv.z * wv.z + hv.w * wv.w;
    #pragma unroll
    for (int off = 1; off < 64; off <<= 1) s += __shfl_xor(s, off);
    if (lane == 0) out[node] = s + b[0];
}

// ---------------- diagnostic fallback --------------------------------------
__global__ void diag_k(float* out, int n, float val)
{
    int t = blockIdx.x * 256 + threadIdx.x;
    if (t < n) out[t] = val;
}

// ---------------------------------------------------------------------------
extern "C" void kernel_launch(void* const* d_in, const int* in_sizes, int n_in,
                              void* d_out, int out_size, void* d_ws, size_t ws_size,
                              hipStream_t stream)
{
    const float* x_a  = (const float*)d_in[0];
    const float* x_b  = (const float*)d_in[1];
    const int*   e_ab = (const int*)d_in[2];
    const int*   e_ba = (const int*)d_in[3];
    const float* wl1  = (const float*)d_in[4];
    const float* wr1  = (const float*)d_in[5];
    const float* b1   = (const float*)d_in[6];
    const float* wl2  = (const float*)d_in[7];
    const float* wr2  = (const float*)d_in[8];
    const float* b2   = (const float*)d_in[9];
    const float* outw = (const float*)d_in[10];
    const float* outb = (const float*)d_in[11];
    const float* mpw  = (const float*)d_in[12];
    const float* ipw  = (const float*)d_in[13];  // [768,256]
    const float* ipb  = (const float*)d_in[14];  // [768]
    const float* aow  = (const float*)d_in[15];  // [256,256]
    const float* aob  = (const float*)d_in[16];
    const float* m1w  = (const float*)d_in[17];
    const float* m1b  = (const float*)d_in[18];
    const float* m2w  = (const float*)d_in[19];
    const float* m2b  = (const float*)d_in[20];
    float* out = (float*)d_out;

    // ---- workspace layout (same NEED as round 4; CSR overlays dead zones) --
    const size_t SZ_ZREG = 40960000, SZ_ACCB = 82240000, SZ_HB = 40960000,
                 SZ_EMBS = 81920000, SZ_WT1 = 786432, SZ_WT2 = 262144;
    const size_t NEED = SZ_ZREG + SZ_ACCB + SZ_HB + SZ_EMBS + SZ_WT1 + SZ_WT2;

    if (ws_size < NEED || n_in < 21 || out_size != N_A) {
        float diag = (float)((ws_size / (1024ull * 1024ull)) * 100ull + (size_t)n_in);
        diag_k<<<(out_size + 255) / 256, 256, 0, stream>>>(out, out_size, diag);
        return;
    }

    char* base = (char*)d_ws;
    float*  ZREG = (float*)base;                                  // 40.96 MB
    float*  ACCB = (float*)(base + SZ_ZREG);                      // 82.24 MB
    __half* HBH  = (__half*)(base + SZ_ZREG + SZ_ACCB);           // 40.96 MB
    float*  HBF  = (float*)(base + SZ_ZREG + SZ_ACCB);
    __half* EMBS = (__half*)(base + SZ_ZREG + SZ_ACCB + SZ_HB);   // 81.92 MB
    float*  WT1  = (float*)(base + SZ_ZREG + SZ_ACCB + SZ_HB + SZ_EMBS);
    float*  WT2  = (float*)(base + SZ_ZREG + SZ_ACCB + SZ_HB + SZ_EMBS + SZ_WT1);
    // overlays
    float* MEANB = ACCB;                 // [N_B,256] fp32 (81.92 MB)
    float* MEANA = ACCB;                 // [N_A,256] fp32 (40.96 MB)
    float* QKVC  = ACCB;
    float* TMLP  = ACCB;
    float* T1    = ZREG;
    float* HA    = ZREG;
    float* POOL  = ZREG;
    float* TPROJ = HBF;
    // CSR-B (dst in [0,N_B)) lives in the HB region (dead until h_b gemm):
    int* cntB  = (int*)HBH;
    int* startB = cntB + N_B;
    int* cursB  = cntB + 2 * N_B;
    int* eidxB  = cntB + 3 * N_B;        // +250k ints: 1.96 MB total << 41 MB
    // CSR-A (dst in [0,N_A)) lives in the ZREG region (z dead after gather1):
    int* cntA  = (int*)ZREG;
    int* startA = cntA + N_A;
    int* cursA  = cntA + 2 * N_A;
    int* eidxA  = cntA + 3 * N_A;        // 1.48 MB << 41 MB

    transpose_k<<<(768 * 256 + 255) / 256, 256, 0, stream>>>(ipw, WT1, 768, 256);
    transpose_k<<<(256 * 256 + 255) / 256, 256, 0, stream>>>(aow, WT2, 256, 256);

    const int EB = (EDG + 255) / 256;

    for (int m = 0; m < MP; ++m) {
        const size_t wo = (size_t)m * CDIM * CDIM;
        const int* sab = e_ab + (size_t)m * 2 * EDG;
        const int* dab = sab + EDG;
        const int* sba = e_ba + (size_t)m * 2 * EDG;
        const int* dba = sba + EDG;

        // z = x_a @ wl1[m]  (pre-transform; linearity of segment mean)
        gemm_k<float, float, 0, false, false, false>
            <<<dim3(4, N_A / 64), 256, 0, stream>>>(
            x_a, CDIM, wl1 + wo, CDIM, nullptr, nullptr, 0, nullptr, 0,
            ZREG, CDIM, CDIM);
        // CSR over ab edges (dst in B)
        hipMemsetAsync(cntB, 0, (size_t)N_B * 4, stream);
        hist_k<<<EB, 256, 0, stream>>>(dab, cntB, EDG);
        scan_k<<<1, 1024, 0, stream>>>(cntB, startB, cursB, N_B);
        fill_k<<<EB, 256, 0, stream>>>(sab, dab, cursB, eidxB, EDG);
        // mean_b = gather-mean of z rows
        gather_mean_k<float><<<N_B / 4, 256, 0, stream>>>(
            ZREG, startB, cntB, eidxB, MEANB, N_B);
        // h_b = relu(x_b @ wr1[m] + b1[m] + mean_b)  -> fp16 (kills CSR-B: ok)
        gemm_k<float, __half, 1, true, true, false>
            <<<dim3(4, N_B / 64), 256, 0, stream>>>(
            x_b, CDIM, wr1 + wo, CDIM, b1 + (size_t)m * CDIM, MEANB, CDIM,
            nullptr, 0, HBH, CDIM, CDIM);
        // CSR over ba edges (dst in A) -- z is dead, reuse ZREG region
        hipMemsetAsync(cntA, 0, (size_t)N_A * 4, stream);
        hist_k<<<EB, 256, 0, stream>>>(dba, cntA, EDG);
        scan_k<<<1, 1024, 0, stream>>>(cntA, startA, cursA, N_A);
        fill_k<<<EB, 256, 0, stream>>>(sba, dba, cursA, eidxA, EDG);
        // mean_a = gather-mean of h_b rows (fp16 source)
        gather_mean_k<__half><<<N_A / 4, 256, 0, stream>>>(
            HBH, startA, cntA, eidxA, MEANA, N_A);
        // t1 = mean_a @ wl2[m]   (writes ZREG: CSR-A dead now)
        gemm_k<float, float, 0, false, false, false>
            <<<dim3(4, N_A / 64), 256, 0, stream>>>(
            MEANA, CDIM, wl2 + wo, CDIM, nullptr, nullptr, 0, nullptr, 0,
            T1, CDIM, CDIM);
        // h_a = relu(x_a @ wr2[m] + b2[m] + t1)   (C aliases extra: safe, 1:1)
        gemm_k<float, float, 1, true, true, false>
            <<<dim3(4, N_A / 64), 256, 0, stream>>>(
            x_a, CDIM, wr2 + wo, CDIM, b2 + (size_t)m * CDIM, T1, CDIM,
            nullptr, 0, HA, CDIM, CDIM);
        // embs[:,m,:] = (h_a @ outw[m] + outb[m]) * mp_weights[m]  -> fp16
        gemm_k<float, __half, 0, true, false, true>
            <<<dim3(4, N_A / 64), 256, 0, stream>>>(
            HA, CDIM, outw + wo, CDIM, outb + (size_t)m * CDIM, nullptr, 0,
            mpw, m, EMBS + (size_t)m * CDIM, 1024, CDIM);
    }

    // phase 2: chunked qkv + fused attention/pool
    const int CH = 4000;  // nodes per chunk -> 16000 rows (divisible by 64)
    for (int ch = 0; ch < N_A / CH; ++ch) {
        const int n0 = ch * CH;
        gemm_k<__half, float, 0, true, false, false>
            <<<dim3(12, (CH * 4) / 64), 256, 0, stream>>>(
            EMBS + (size_t)n0 * 1024, CDIM, WT1, 768, ipb, nullptr, 0,
            nullptr, 0, QKVC, 768, CDIM);
        attn_pool_k<<<CH / 4, 256, 0, stream>>>(QKVC, POOL + (size_t)n0 * 256, CH);
    }
    // tproj = pooled @ attn_out_w.T + aob   (POOL=ZREG -> TPROJ=HB region)
    gemm_k<float, float, 0, true, false, false>
        <<<dim3(4, N_A / 64), 256, 0, stream>>>(
        POOL, CDIM, WT2, CDIM, aob, nullptr, 0, nullptr, 0, TPROJ, CDIM, CDIM);
    // tmlp = relu(tproj @ mlp1_w + m1b)     (-> ACCB region, QKVC dead)
    gemm_k<float, float, 0, true, true, false>
        <<<dim3(4, N_A / 64), 256, 0, stream>>>(
        TPROJ, CDIM, m1w, CDIM, m1b, nullptr, 0, nullptr, 0, TMLP, CDIM, CDIM);
    mlp2_k<<<(N_A * 64) / 256, 256, 0, stream>>>(TMLP, m2w, m2b, out, N_A);
}

// Round 7
// 1725.805 us; speedup vs baseline: 5.7807x; 2.6770x over previous
//
#include <hip/hip_runtime.h>
#include <hip/hip_bf16.h>
#include <hip/hip_fp16.h>

// ---------------------------------------------------------------------------
// MPSGNN: 4 metapath SAGE GNNs + metapath attention + MLP head.
// N_A=40000, N_B=80000, C=256, M=4, E=250000, heads=4 (d=64)
// Round 7: (1) parallel 3-phase CSR scan (was 175us x8 single-block serial);
// (2) all GEMMs -> MFMA fp16 (16x16x32, fp32 acc), weights pre-converted to
// fp16 BT[n][k]; z/means stored fp16. Gate/NEED unchanged (247MB).
// ---------------------------------------------------------------------------

#define N_A 40000
#define N_B 80000
#define CDIM 256
#define MP 4
#define EDG 250000

using f16x8 = __attribute__((ext_vector_type(8))) _Float16;
using f32x4 = __attribute__((ext_vector_type(4))) float;

// ---- dtype helpers --------------------------------------------------------
__device__ __forceinline__ float ldf(const float* p) { return *p; }
__device__ __forceinline__ float ldf(const __half* p) { return __half2float(*p); }
__device__ __forceinline__ void stf(float* p, float v) { *p = v; }
__device__ __forceinline__ void stf(__half* p, float v) { *p = __float2half(v); }

__device__ __forceinline__ float4 ld4(const __half* p) {
    __half2 a = *(const __half2*)p, b = *(const __half2*)(p + 2);
    float2 fa = __half22float2(a), fb = __half22float2(b);
    return make_float4(fa.x, fa.y, fb.x, fb.y);
}

// ---------------- MFMA GEMM: C[M,N] = act(A[M,K] @ BT[N,K]^T + ...) --------
// Tile 64(M) x 128(N), BK=32, 256 threads = 4 waves (2x2), each wave 32x64.
// A: row-major [M,K] (fp32 or fp16). BT: fp16 [N][K] row-major.
// Frag layout (16x16x32): A/B: elem lane&15, k=(lane>>4)*8+j.
//                         C/D: col=lane&15, row=(lane>>4)*4+reg.
template<typename AT, typename CT, typename ET, bool EXTRA, bool BIAS,
         bool RELU, bool OSCALE>
__global__ __launch_bounds__(256) void mgemm_k(
    const AT* __restrict__ A, int lda,
    const __half* __restrict__ BT,
    const float* __restrict__ bias,
    const ET* __restrict__ extra, int lde,
    const float* __restrict__ osp, int osi,
    CT* __restrict__ C, int ldc, int K)
{
    __shared__ __align__(16) _Float16 As[64 * 40];   // [m][k], pad 40: 80B rows
    __shared__ __align__(16) _Float16 Bs[128 * 40];  // [n][k]
    const int tid = threadIdx.x;
    const int w = tid >> 6, lane = tid & 63;
    const int wm = w & 1, wn = w >> 1;
    const int lr = lane & 15, kb = lane >> 4;
    const long long row0 = (long long)blockIdx.y * 64;
    const int col0 = blockIdx.x * 128;
    f32x4 acc[2][4] = {};
    for (int k0 = 0; k0 < K; k0 += 32) {
        // stage A: 64 rows x 32 k (8 elems/thread, 16B LDS writes)
        {
            int flat = tid * 8;
            int r = flat >> 5, c = flat & 31;
            const AT* src = &A[(row0 + r) * lda + k0 + c];
            if constexpr (sizeof(AT) == 4) {
                float4 v0 = *(const float4*)(src);
                float4 v1 = *(const float4*)(src + 4);
                _Float16 h[8] = {(_Float16)v0.x, (_Float16)v0.y, (_Float16)v0.z,
                                 (_Float16)v0.w, (_Float16)v1.x, (_Float16)v1.y,
                                 (_Float16)v1.z, (_Float16)v1.w};
                *(f16x8*)&As[r * 40 + c] = *(f16x8*)h;
            } else {
                *(f16x8*)&As[r * 40 + c] = *(const f16x8*)src;
            }
        }
        // stage B: 128 rows x 32 k from BT (2x 16B chunks/thread)
        {
            #pragma unroll
            for (int q = 0; q < 2; ++q) {
                int cid = tid * 2 + q;
                int r = cid >> 2, cc = cid & 3;
                *(f16x8*)&Bs[r * 40 + cc * 8] =
                    *(const f16x8*)&BT[(long long)(col0 + r) * K + k0 + cc * 8];
            }
        }
        __syncthreads();
        f16x8 af[2], bf[4];
        #pragma unroll
        for (int i = 0; i < 2; ++i)
            af[i] = *(f16x8*)&As[(wm * 32 + i * 16 + lr) * 40 + kb * 8];
        #pragma unroll
        for (int j = 0; j < 4; ++j)
            bf[j] = *(f16x8*)&Bs[(wn * 64 + j * 16 + lr) * 40 + kb * 8];
        #pragma unroll
        for (int i = 0; i < 2; ++i)
            #pragma unroll
            for (int j = 0; j < 4; ++j)
                acc[i][j] = __builtin_amdgcn_mfma_f32_16x16x32_f16(
                    af[i], bf[j], acc[i][j], 0, 0, 0);
        __syncthreads();
    }
    float osc = 1.0f;
    if (OSCALE) osc = osp[osi];
    #pragma unroll
    for (int i = 0; i < 2; ++i) {
        #pragma unroll
        for (int j = 0; j < 4; ++j) {
            #pragma unroll
            for (int r = 0; r < 4; ++r) {
                long long rg = row0 + wm * 32 + i * 16 + (lane >> 4) * 4 + r;
                int cg = col0 + wn * 64 + j * 16 + (lane & 15);
                float v = acc[i][j][r];
                if (EXTRA) v += ldf(&extra[rg * lde + cg]);
                if (BIAS) v += bias[cg];
                if (RELU) v = fmaxf(v, 0.0f);
                if (OSCALE) v *= osc;
                stf(&C[rg * ldc + cg], v);
            }
        }
    }
}

// ---------------- weight conversion (fp32 -> fp16, opt. transpose) ---------
__global__ void cvt_flat_k(const float* __restrict__ s, __half* __restrict__ d, int n)
{
    int t = blockIdx.x * 256 + threadIdx.x;
    if (t < n) d[t] = __float2half(s[t]);
}
// ns slices of [256][256]: d[m][c][r] = s[m][r][c]
__global__ void cvt_tr_k(const float* __restrict__ s, __half* __restrict__ d, int ns)
{
    int t = blockIdx.x * 256 + threadIdx.x;
    if (t >= ns * 65536) return;
    int m = t >> 16, i = t & 65535;
    int r = i >> 8, c = i & 255;
    d[(m << 16) + (c << 8) + r] = __float2half(s[t]);
}

// ---------------- CSR build: hist -> 3-phase scan -> fill ------------------
__global__ __launch_bounds__(256) void hist_k(
    const int* __restrict__ dst, int* __restrict__ cnt, int E)
{
    int e = blockIdx.x * 256 + threadIdx.x;
    if (e < E) atomicAdd(&cnt[dst[e]], 1);
}

__global__ __launch_bounds__(256) void scan_blk_k(
    const int* __restrict__ cnt, int* __restrict__ bsum, int n)
{
    __shared__ int s[256];
    int t = threadIdx.x, i = blockIdx.x * 256 + t;
    s[t] = (i < n) ? cnt[i] : 0;
    __syncthreads();
    for (int off = 128; off > 0; off >>= 1) {
        if (t < off) s[t] += s[t + off];
        __syncthreads();
    }
    if (t == 0) bsum[blockIdx.x] = s[0];
}

__global__ __launch_bounds__(512) void scan_top_k(
    const int* __restrict__ bsum, int* __restrict__ boff, int nb)
{
    __shared__ int s[512];
    int t = threadIdx.x;
    int v = (t < nb) ? bsum[t] : 0;
    s[t] = v;
    __syncthreads();
    for (int off = 1; off < 512; off <<= 1) {
        int u = (t >= off) ? s[t - off] : 0;
        __syncthreads();
        s[t] += u;
        __syncthreads();
    }
    if (t < nb) boff[t] = s[t] - v;  // exclusive
}

__global__ __launch_bounds__(256) void scan_fin_k(
    const int* __restrict__ cnt, const int* __restrict__ boff,
    int* __restrict__ start, int* __restrict__ cursor, int n)
{
    __shared__ int s[256];
    int t = threadIdx.x, i = blockIdx.x * 256 + t;
    int v = (i < n) ? cnt[i] : 0;
    s[t] = v;
    __syncthreads();
    for (int off = 1; off < 256; off <<= 1) {
        int u = (t >= off) ? s[t - off] : 0;
        __syncthreads();
        s[t] += u;
        __syncthreads();
    }
    if (i < n) {
        int ex = boff[blockIdx.x] + s[t] - v;
        start[i] = ex;
        cursor[i] = ex;
    }
}

__global__ __launch_bounds__(256) void fill_k(
    const int* __restrict__ src, const int* __restrict__ dst,
    int* __restrict__ cursor, int* __restrict__ eidx, int E)
{
    int e = blockIdx.x * 256 + threadIdx.x;
    if (e < E) {
        int p = atomicAdd(&cursor[dst[e]], 1);
        eidx[p] = src[e];
    }
}

// ---------------- gather-mean (fp16 in, fp16 out) --------------------------
__global__ __launch_bounds__(256) void gather_mean_k(
    const __half* __restrict__ feat, const int* __restrict__ start,
    const int* __restrict__ cnt, const int* __restrict__ eidx,
    __half* __restrict__ mean, int n)
{
    int t = blockIdx.x * 256 + threadIdx.x;
    int r = t >> 6, lane = t & 63;
    if (r >= n) return;
    const int s0 = start[r], deg = cnt[r];
    float4 acc = make_float4(0.f, 0.f, 0.f, 0.f);
    for (int i = 0; i < deg; ++i) {
        int s = eidx[s0 + i];
        float4 v = ld4(&feat[(long long)s * CDIM + lane * 4]);
        acc.x += v.x; acc.y += v.y; acc.z += v.z; acc.w += v.w;
    }
    const float inv = 1.0f / fmaxf((float)deg, 1.0f);
    __half hv[4] = {__float2half(acc.x * inv), __float2half(acc.y * inv),
                    __float2half(acc.z * inv), __float2half(acc.w * inv)};
    *(float2*)&mean[(long long)r * CDIM + lane * 4] = *(float2*)hv;
}

// ---------------- fused per-node attention + mean pool ---------------------
__global__ __launch_bounds__(256) void attn_pool_k(
    const float* __restrict__ qkv, float* __restrict__ pooled, int nNodes)
{
    __shared__ float sh[4][3072];
    __shared__ float sW[4][16];
    const int tid = threadIdx.x;
    const int wid = tid >> 6, lane = tid & 63;
    const int node = blockIdx.x * 4 + wid;   // nNodes % 4 == 0: never OOB
    float* S = sh[wid];
    const float* base = qkv + (long long)node * 4 * 768;
    #pragma unroll
    for (int it = 0; it < 12; ++it) {
        int f = lane + it * 64;
        *(float4*)&S[f * 4] = *(const float4*)&base[f * 4];
    }
    __syncthreads();
    const int h = lane >> 4, qm = (lane >> 2) & 3, km = lane & 3;
    const float* qrow = &S[qm * 768 + h * 64];
    const float* krow = &S[km * 768 + 256 + h * 64];
    float s = 0.0f;
    #pragma unroll
    for (int i = 0; i < 64; ++i) s = fmaf(qrow[i], krow[i], s);
    s *= 0.125f;  // 1/sqrt(64)
    float mx = fmaxf(s, __shfl_xor(s, 1));
    mx = fmaxf(mx, __shfl_xor(mx, 2));
    float e = __expf(s - mx);
    float sum = e + __shfl_xor(e, 1);
    sum += __shfl_xor(sum, 2);
    float a = e / sum;
    float tt = a + __shfl_xor(a, 4);
    tt += __shfl_xor(tt, 8);
    if (qm == 0) sW[wid][h * 4 + km] = 0.25f * tt;
    __syncthreads();
    #pragma unroll
    for (int j = 0; j < 4; ++j) {
        int c = j * 64 + lane;
        float p = 0.0f;
        #pragma unroll
        for (int kk = 0; kk < 4; ++kk)
            p = fmaf(sW[wid][j * 4 + kk], S[kk * 768 + 512 + c], p);
        pooled[(long long)node * 256 + c] = p;
    }
}

// ---------------- final: out[n] = h[n] . mlp2_w + mlp2_b -------------------
__global__ __launch_bounds__(256) void mlp2_k(
    const float* __restrict__ h, const float* __restrict__ w,
    const float* __restrict__ b, float* __restrict__ out, int n)
{
    int t = blockIdx.x * 256 + threadIdx.x;
    int node = t >> 6, lane = t & 63;
    if (node >= n) return;
    const float4 hv = *(const float4*)&h[(long long)node * CDIM + lane * 4];
    const float4 wv = *(const float4*)&w[lane * 4];
    float s = hv.x * wv.x + hv.y * wv.y + hv.z * wv.z + hv.w * wv.w;
    #pragma unroll
    for (int off = 1; off < 64; off <<= 1) s += __shfl_xor(s, off);
    if (lane == 0) out[node] = s + b[0];
}

// ---------------- diagnostic fallback --------------------------------------
__global__ void diag_k(float* out, int n, float val)
{
    int t = blockIdx.x * 256 + threadIdx.x;
    if (t < n) out[t] = val;
}

// ---------------------------------------------------------------------------
extern "C" void kernel_launch(void* const* d_in, const int* in_sizes, int n_in,
                              void* d_out, int out_size, void* d_ws, size_t ws_size,
                              hipStream_t stream)
{
    const float* x_a  = (const float*)d_in[0];
    const float* x_b  = (const float*)d_in[1];
    const int*   e_ab = (const int*)d_in[2];
    const int*   e_ba = (const int*)d_in[3];
    const float* wl1  = (const float*)d_in[4];
    const float* wr1  = (const float*)d_in[5];
    const float* b1   = (const float*)d_in[6];
    const float* wl2  = (const float*)d_in[7];
    const float* wr2  = (const float*)d_in[8];
    const float* b2   = (const float*)d_in[9];
    const float* outw = (const float*)d_in[10];
    const float* outb = (const float*)d_in[11];
    const float* mpw  = (const float*)d_in[12];
    const float* ipw  = (const float*)d_in[13];  // [768,256]
    const float* ipb  = (const float*)d_in[14];  // [768]
    const float* aow  = (const float*)d_in[15];  // [256,256]
    const float* aob  = (const float*)d_in[16];
    const float* m1w  = (const float*)d_in[17];
    const float* m1b  = (const float*)d_in[18];
    const float* m2w  = (const float*)d_in[19];
    const float* m2b  = (const float*)d_in[20];
    float* out = (float*)d_out;

    // ---- workspace layout (NEED unchanged from rounds 4-6) ----
    const size_t SZ_ZREG = 40960000, SZ_ACCB = 82240000, SZ_HB = 40960000,
                 SZ_EMBS = 81920000, SZ_WT1 = 786432, SZ_WT2 = 262144;
    const size_t NEED = SZ_ZREG + SZ_ACCB + SZ_HB + SZ_EMBS + SZ_WT1 + SZ_WT2;

    if (ws_size < NEED || n_in < 21 || out_size != N_A) {
        float diag = (float)((ws_size / (1024ull * 1024ull)) * 100ull + (size_t)n_in);
        diag_k<<<(out_size + 255) / 256, 256, 0, stream>>>(out, out_size, diag);
        return;
    }

    char* base = (char*)d_ws;
    float*  ZREG = (float*)base;                                  // 40.96 MB
    char*   ACCBc = base + SZ_ZREG;                               // 82.24 MB
    __half* HBH  = (__half*)(base + SZ_ZREG + SZ_ACCB);           // 40.96 MB
    float*  HBF  = (float*)(base + SZ_ZREG + SZ_ACCB);
    __half* EMBS = (__half*)(base + SZ_ZREG + SZ_ACCB + SZ_HB);   // 81.92 MB

    // ACCB region uses (max 49.2MB at offset 0): means / QKVC / TMLP.
    __half* MEANBH = (__half*)ACCBc;           // [N_B,256] fp16 = 40.96 MB
    __half* MEANAH = (__half*)ACCBc;           // [N_A,256] fp16 = 20.48 MB
    float*  QKVC   = (float*)ACCBc;            // 16000x768 fp32 = 49.15 MB
    float*  TMLP   = (float*)ACCBc;            // 40.96 MB
    // fp16 weights parked in ACCB tail (no overlay reaches past 49.2MB):
    __half* WH     = (__half*)(ACCBc + 78905344);  // 3.28 MB, 16B aligned
    __half* WL1T = WH;                 // 4x[256][256] BT
    __half* WR1T = WH + 262144;
    __half* WL2T = WH + 524288;
    __half* WR2T = WH + 786432;
    __half* OUTWT = WH + 1048576;
    __half* IPW16 = WH + 1310720;      // [768][256] (no transpose)
    __half* AOW16 = WH + 1507328;      // [256][256] (no transpose)
    __half* M1WT  = WH + 1572864;      // [256][256] BT
    // other overlays
    __half* ZH    = (__half*)ZREG;     // z fp16 [N_A,256] = 20.48 MB
    float*  T1    = ZREG;              // fp32 [N_A,256]
    float*  HA    = ZREG;
    float*  POOL  = ZREG;
    float*  TPROJ = HBF;
    // CSR-B in HB region (dead until h_b gemm writes HBH):
    int* cntB   = (int*)HBH;
    int* startB = cntB + N_B;
    int* cursB  = cntB + 2 * N_B;
    int* eidxB  = cntB + 3 * N_B;
    int* bsumB  = eidxB + EDG;
    int* boffB  = bsumB + 512;
    // CSR-A in ZREG region (z dead after gather-B):
    int* cntA   = (int*)ZREG;
    int* startA = cntA + N_A;
    int* cursA  = cntA + 2 * N_A;
    int* eidxA  = cntA + 3 * N_A;
    int* bsumA  = eidxA + EDG;
    int* boffA  = bsumA + 512;

    // ---- one-time (per call) fp16 weight conversion ----
    cvt_tr_k<<<1024, 256, 0, stream>>>(wl1, WL1T, 4);
    cvt_tr_k<<<1024, 256, 0, stream>>>(wr1, WR1T, 4);
    cvt_tr_k<<<1024, 256, 0, stream>>>(wl2, WL2T, 4);
    cvt_tr_k<<<1024, 256, 0, stream>>>(wr2, WR2T, 4);
    cvt_tr_k<<<1024, 256, 0, stream>>>(outw, OUTWT, 4);
    cvt_tr_k<<<256, 256, 0, stream>>>(m1w, M1WT, 1);
    cvt_flat_k<<<768, 256, 0, stream>>>(ipw, IPW16, 196608);
    cvt_flat_k<<<256, 256, 0, stream>>>(aow, AOW16, 65536);

    const int EB = (EDG + 255) / 256;
    const int NBB = (N_B + 255) / 256;   // 313
    const int NBA = (N_A + 255) / 256;   // 157

    for (int m = 0; m < MP; ++m) {
        const int* sab = e_ab + (size_t)m * 2 * EDG;
        const int* dab = sab + EDG;
        const int* sba = e_ba + (size_t)m * 2 * EDG;
        const int* dba = sba + EDG;

        // z = x_a @ wl1[m]  -> fp16 ZH
        mgemm_k<float, __half, float, false, false, false, false>
            <<<dim3(2, N_A / 64), 256, 0, stream>>>(
            x_a, CDIM, WL1T + m * 65536, nullptr, nullptr, 0, nullptr, 0,
            ZH, CDIM, CDIM);
        // CSR over ab edges (dst in B)
        hipMemsetAsync(cntB, 0, (size_t)N_B * 4, stream);
        hist_k<<<EB, 256, 0, stream>>>(dab, cntB, EDG);
        scan_blk_k<<<NBB, 256, 0, stream>>>(cntB, bsumB, N_B);
        scan_top_k<<<1, 512, 0, stream>>>(bsumB, boffB, NBB);
        scan_fin_k<<<NBB, 256, 0, stream>>>(cntB, boffB, startB, cursB, N_B);
        fill_k<<<EB, 256, 0, stream>>>(sab, dab, cursB, eidxB, EDG);
        gather_mean_k<<<N_B / 4, 256, 0, stream>>>(
            ZH, startB, cntB, eidxB, MEANBH, N_B);
        // h_b = relu(x_b @ wr1[m] + b1[m] + mean_b)  -> fp16 (kills CSR-B)
        mgemm_k<float, __half, __half, true, true, true, false>
            <<<dim3(2, N_B / 64), 256, 0, stream>>>(
            x_b, CDIM, WR1T + m * 65536, b1 + (size_t)m * CDIM, MEANBH, CDIM,
            nullptr, 0, HBH, CDIM, CDIM);
        // CSR over ba edges (dst in A) -- z dead, reuse ZREG
        hipMemsetAsync(cntA, 0, (size_t)N_A * 4, stream);
        hist_k<<<EB, 256, 0, stream>>>(dba, cntA, EDG);
        scan_blk_k<<<NBA, 256, 0, stream>>>(cntA, bsumA, N_A);
        scan_top_k<<<1, 512, 0, stream>>>(bsumA, boffA, NBA);
        scan_fin_k<<<NBA, 256, 0, stream>>>(cntA, boffA, startA, cursA, N_A);
        fill_k<<<EB, 256, 0, stream>>>(sba, dba, cursA, eidxA, EDG);
        gather_mean_k<<<N_A / 4, 256, 0, stream>>>(
            HBH, startA, cntA, eidxA, MEANAH, N_A);
        // t1 = mean_a @ wl2[m]  (writes ZREG: CSR-A dead now)
        mgemm_k<__half, float, float, false, false, false, false>
            <<<dim3(2, N_A / 64), 256, 0, stream>>>(
            MEANAH, CDIM, WL2T + m * 65536, nullptr, nullptr, 0, nullptr, 0,
            T1, CDIM, CDIM);
        // h_a = relu(x_a @ wr2[m] + b2[m] + t1)  (C aliases extra 1:1: safe)
        mgemm_k<float, float, float, true, true, true, false>
            <<<dim3(2, N_A / 64), 256, 0, stream>>>(
            x_a, CDIM, WR2T + m * 65536, b2 + (size_t)m * CDIM, T1, CDIM,
            nullptr, 0, HA, CDIM, CDIM);
        // embs[:,m,:] = (h_a @ outw[m] + outb[m]) * mp_weights[m] -> fp16
        mgemm_k<float, __half, float, false, true, false, true>
            <<<dim3(2, N_A / 64), 256, 0, stream>>>(
            HA, CDIM, OUTWT + m * 65536, outb + (size_t)m * CDIM, nullptr, 0,
            mpw, m, EMBS + (size_t)m * CDIM, 1024, CDIM);
    }

    // phase 2: chunked qkv + fused attention/pool
    const int CH = 4000;  // 16000 rows/chunk
    for (int ch = 0; ch < N_A / CH; ++ch) {
        const int n0 = ch * CH;
        mgemm_k<__half, float, float, false, true, false, false>
            <<<dim3(6, (CH * 4) / 64), 256, 0, stream>>>(
            EMBS + (size_t)n0 * 1024, CDIM, IPW16, ipb, nullptr, 0,
            nullptr, 0, QKVC, 768, CDIM);
        attn_pool_k<<<CH / 4, 256, 0, stream>>>(QKVC, POOL + (size_t)n0 * 256, CH);
    }
    // tproj = pooled @ attn_out_w.T + aob   (POOL=ZREG -> TPROJ=HB region)
    mgemm_k<float, float, float, false, true, false, false>
        <<<dim3(2, N_A / 64), 256, 0, stream>>>(
        POOL, CDIM, AOW16, aob, nullptr, 0, nullptr, 0, TPROJ, CDIM, CDIM);
    // tmlp = relu(tproj @ mlp1_w + m1b)  (-> ACCB offset 0; weights at tail)
    mgemm_k<float, float, float, false, true, true, false>
        <<<dim3(2, N_A / 64), 256, 0, stream>>>(
        TPROJ, CDIM, M1WT, m1b, nullptr, 0, nullptr, 0, TMLP, CDIM, CDIM);
    mlp2_k<<<(N_A * 64) / 256, 256, 0, stream>>>(TMLP, m2w, m2b, out, N_A);
}

// Round 9
// 1530.012 us; speedup vs baseline: 6.5204x; 1.1280x over previous
//
#include <hip/hip_runtime.h>
#include <hip/hip_bf16.h>
#include <hip/hip_fp16.h>

// ---------------------------------------------------------------------------
// MPSGNN: 4 metapath SAGE GNNs + metapath attention + MLP head.
// N_A=40000, N_B=80000, C=256, M=4, E=250000, heads=4 (d=64)
// Round 9: identical to round 8 (GPU acquisition timeout; no data).
// Traffic halving: fp16 x_a/x_b (converted once), fused K=512
// [x_a|mean_a]@[wr2;wl2] GEMM (kills T1 round-trip), attn_out folded into
// mlp1 (W_c = aow^T@m1w), fp16 QKV/TMLP. Rotating A/B scratch regions.
// ---------------------------------------------------------------------------

#define N_A 40000
#define N_B 80000
#define CDIM 256
#define MP 4
#define EDG 250000

using f16x8 = __attribute__((ext_vector_type(8))) _Float16;
using f32x4 = __attribute__((ext_vector_type(4))) float;

// ---- dtype helpers --------------------------------------------------------
__device__ __forceinline__ float ldf(const float* p) { return *p; }
__device__ __forceinline__ float ldf(const __half* p) { return __half2float(*p); }
__device__ __forceinline__ void stf(float* p, float v) { *p = v; }
__device__ __forceinline__ void stf(__half* p, float v) { *p = __float2half(v); }

__device__ __forceinline__ float4 ld4(const __half* p) {
    __half2 a = *(const __half2*)p, b = *(const __half2*)(p + 2);
    float2 fa = __half22float2(a), fb = __half22float2(b);
    return make_float4(fa.x, fa.y, fb.x, fb.y);
}

// ---------------- MFMA GEMM: C[M,N] = act(A[M,K] @ BT[N,K]^T + ...) --------
// Tile 64(M) x 128(N), BK=32, 256 threads = 4 waves (2x2), each wave 32x64.
// FUSE2: A is [x | A2] along K (both __half, lda/256), BT pre-concatenated.
template<typename AT, typename CT, typename ET, bool FUSE2, bool EXTRA,
         bool BIAS, bool RELU, bool OSCALE>
__global__ __launch_bounds__(256) void mgemm_k(
    const AT* __restrict__ A, int lda,
    const __half* __restrict__ A2,
    const __half* __restrict__ BT,
    const float* __restrict__ bias,
    const ET* __restrict__ extra, int lde,
    const float* __restrict__ osp, int osi,
    CT* __restrict__ C, int ldc, int K)
{
    __shared__ __align__(16) _Float16 As[64 * 40];   // [m][k], pad 40
    __shared__ __align__(16) _Float16 Bs[128 * 40];  // [n][k]
    const int tid = threadIdx.x;
    const int w = tid >> 6, lane = tid & 63;
    const int wm = w & 1, wn = w >> 1;
    const int lr = lane & 15, kb = lane >> 4;
    const long long row0 = (long long)blockIdx.y * 64;
    const int col0 = blockIdx.x * 128;
    f32x4 acc[2][4] = {};
    for (int k0 = 0; k0 < K; k0 += 32) {
        // stage A: 64 rows x 32 k (8 elems/thread)
        {
            int flat = tid * 8;
            int r = flat >> 5, c = flat & 31;
            int kk = k0 + c;
            if constexpr (FUSE2) {
                const __half* src = (kk < 256)
                    ? (const __half*)&A[(row0 + r) * lda + kk]
                    : &A2[(row0 + r) * 256 + (kk - 256)];
                *(f16x8*)&As[r * 40 + c] = *(const f16x8*)src;
            } else if constexpr (sizeof(AT) == 4) {
                const AT* src = &A[(row0 + r) * lda + kk];
                float4 v0 = *(const float4*)(src);
                float4 v1 = *(const float4*)(src + 4);
                _Float16 h[8] = {(_Float16)v0.x, (_Float16)v0.y, (_Float16)v0.z,
                                 (_Float16)v0.w, (_Float16)v1.x, (_Float16)v1.y,
                                 (_Float16)v1.z, (_Float16)v1.w};
                *(f16x8*)&As[r * 40 + c] = *(f16x8*)h;
            } else {
                *(f16x8*)&As[r * 40 + c] =
                    *(const f16x8*)&A[(row0 + r) * lda + kk];
            }
        }
        // stage B: 128 rows x 32 k from BT
        {
            #pragma unroll
            for (int q = 0; q < 2; ++q) {
                int cid = tid * 2 + q;
                int r = cid >> 2, cc = cid & 3;
                *(f16x8*)&Bs[r * 40 + cc * 8] =
                    *(const f16x8*)&BT[(long long)(col0 + r) * K + k0 + cc * 8];
            }
        }
        __syncthreads();
        f16x8 af[2], bf[4];
        #pragma unroll
        for (int i = 0; i < 2; ++i)
            af[i] = *(f16x8*)&As[(wm * 32 + i * 16 + lr) * 40 + kb * 8];
        #pragma unroll
        for (int j = 0; j < 4; ++j)
            bf[j] = *(f16x8*)&Bs[(wn * 64 + j * 16 + lr) * 40 + kb * 8];
        #pragma unroll
        for (int i = 0; i < 2; ++i)
            #pragma unroll
            for (int j = 0; j < 4; ++j)
                acc[i][j] = __builtin_amdgcn_mfma_f32_16x16x32_f16(
                    af[i], bf[j], acc[i][j], 0, 0, 0);
        __syncthreads();
    }
    float osc = 1.0f;
    if (OSCALE) osc = osp[osi];
    #pragma unroll
    for (int i = 0; i < 2; ++i) {
        #pragma unroll
        for (int j = 0; j < 4; ++j) {
            #pragma unroll
            for (int r = 0; r < 4; ++r) {
                long long rg = row0 + wm * 32 + i * 16 + (lane >> 4) * 4 + r;
                int cg = col0 + wn * 64 + j * 16 + (lane & 15);
                float v = acc[i][j][r];
                if (EXTRA) v += ldf(&extra[rg * lde + cg]);
                if (BIAS) v += bias[cg];
                if (RELU) v = fmaxf(v, 0.0f);
                if (OSCALE) v *= osc;
                stf(&C[rg * ldc + cg], v);
            }
        }
    }
}

// ---------------- conversion kernels ---------------------------------------
__global__ void cvt8_k(const float* __restrict__ s, __half* __restrict__ d, int n8)
{
    int t = blockIdx.x * 256 + threadIdx.x;
    if (t >= n8) return;
    const float4 a = *(const float4*)&s[t * 8];
    const float4 b = *(const float4*)&s[t * 8 + 4];
    _Float16 h[8] = {(_Float16)a.x, (_Float16)a.y, (_Float16)a.z, (_Float16)a.w,
                     (_Float16)b.x, (_Float16)b.y, (_Float16)b.z, (_Float16)b.w};
    *(f16x8*)&d[t * 8] = *(f16x8*)h;
}
__global__ void cvt_flat_k(const float* __restrict__ s, __half* __restrict__ d, int n)
{
    int t = blockIdx.x * 256 + threadIdx.x;
    if (t < n) d[t] = __float2half(s[t]);
}
// ns slices of [256][256]: d[m][c][r] = s[m][r][c]
__global__ void cvt_tr_k(const float* __restrict__ s, __half* __restrict__ d, int ns)
{
    int t = blockIdx.x * 256 + threadIdx.x;
    if (t >= ns * 65536) return;
    int m = t >> 16, i = t & 65535;
    int r = i >> 8, c = i & 255;
    d[(m << 16) + (c << 8) + r] = __float2half(s[t]);
}
// BT2[m][n][k]: k<256 -> wr2[m][k][n]; k>=256 -> wl2[m][k-256][n]
__global__ void cvt_bt2_k(const float* __restrict__ wr2,
                          const float* __restrict__ wl2, __half* __restrict__ d)
{
    int t = blockIdx.x * 256 + threadIdx.x;
    if (t >= 4 * 256 * 512) return;
    int m = t >> 17, i = t & 131071;
    int n = i >> 9, k = i & 511;
    float v = (k < 256) ? wr2[(m << 16) + (k << 8) + n]
                        : wl2[(m << 16) + ((k - 256) << 8) + n];
    d[t] = __float2half(v);
}
// WcT[n][k] = sum_j aow[j][k] * m1w[j][n]
__global__ void wc_k(const float* __restrict__ aow, const float* __restrict__ m1w,
                     __half* __restrict__ wct)
{
    int t = blockIdx.x * 256 + threadIdx.x;
    if (t >= 65536) return;
    int n = t >> 8, k = t & 255;
    float s = 0.0f;
    for (int j = 0; j < 256; ++j)
        s = fmaf(aow[j * 256 + k], m1w[j * 256 + n], s);
    wct[t] = __float2half(s);
}
// bc[n] = sum_j aob[j]*m1w[j][n] + m1b[n]
__global__ void bc_k(const float* __restrict__ aob, const float* __restrict__ m1w,
                     const float* __restrict__ m1b, float* __restrict__ bc)
{
    int n = threadIdx.x;
    float s = m1b[n];
    for (int j = 0; j < 256; ++j) s = fmaf(aob[j], m1w[j * 256 + n], s);
    bc[n] = s;
}

// ---------------- CSR build: hist -> 3-phase scan -> fill ------------------
__global__ __launch_bounds__(256) void hist_k(
    const int* __restrict__ dst, int* __restrict__ cnt, int E)
{
    int e = blockIdx.x * 256 + threadIdx.x;
    if (e < E) atomicAdd(&cnt[dst[e]], 1);
}
__global__ __launch_bounds__(256) void scan_blk_k(
    const int* __restrict__ cnt, int* __restrict__ bsum, int n)
{
    __shared__ int s[256];
    int t = threadIdx.x, i = blockIdx.x * 256 + t;
    s[t] = (i < n) ? cnt[i] : 0;
    __syncthreads();
    for (int off = 128; off > 0; off >>= 1) {
        if (t < off) s[t] += s[t + off];
        __syncthreads();
    }
    if (t == 0) bsum[blockIdx.x] = s[0];
}
__global__ __launch_bounds__(512) void scan_top_k(
    const int* __restrict__ bsum, int* __restrict__ boff, int nb)
{
    __shared__ int s[512];
    int t = threadIdx.x;
    int v = (t < nb) ? bsum[t] : 0;
    s[t] = v;
    __syncthreads();
    for (int off = 1; off < 512; off <<= 1) {
        int u = (t >= off) ? s[t - off] : 0;
        __syncthreads();
        s[t] += u;
        __syncthreads();
    }
    if (t < nb) boff[t] = s[t] - v;  // exclusive
}
__global__ __launch_bounds__(256) void scan_fin_k(
    const int* __restrict__ cnt, const int* __restrict__ boff,
    int* __restrict__ start, int* __restrict__ cursor, int n)
{
    __shared__ int s[256];
    int t = threadIdx.x, i = blockIdx.x * 256 + t;
    int v = (i < n) ? cnt[i] : 0;
    s[t] = v;
    __syncthreads();
    for (int off = 1; off < 256; off <<= 1) {
        int u = (t >= off) ? s[t - off] : 0;
        __syncthreads();
        s[t] += u;
        __syncthreads();
    }
    if (i < n) {
        int ex = boff[blockIdx.x] + s[t] - v;
        start[i] = ex;
        cursor[i] = ex;
    }
}
__global__ __launch_bounds__(256) void fill_k(
    const int* __restrict__ src, const int* __restrict__ dst,
    int* __restrict__ cursor, int* __restrict__ eidx, int E)
{
    int e = blockIdx.x * 256 + threadIdx.x;
    if (e < E) {
        int p = atomicAdd(&cursor[dst[e]], 1);
        eidx[p] = src[e];
    }
}

// ---------------- gather-mean (fp16 in, fp16 out) --------------------------
__global__ __launch_bounds__(256) void gather_mean_k(
    const __half* __restrict__ feat, const int* __restrict__ start,
    const int* __restrict__ cnt, const int* __restrict__ eidx,
    __half* __restrict__ mean, int n)
{
    int t = blockIdx.x * 256 + threadIdx.x;
    int r = t >> 6, lane = t & 63;
    if (r >= n) return;
    const int s0 = start[r], deg = cnt[r];
    float4 acc = make_float4(0.f, 0.f, 0.f, 0.f);
    for (int i = 0; i < deg; ++i) {
        int s = eidx[s0 + i];
        float4 v = ld4(&feat[(long long)s * CDIM + lane * 4]);
        acc.x += v.x; acc.y += v.y; acc.z += v.z; acc.w += v.w;
    }
    const float inv = 1.0f / fmaxf((float)deg, 1.0f);
    __half hv[4] = {__float2half(acc.x * inv), __float2half(acc.y * inv),
                    __float2half(acc.z * inv), __float2half(acc.w * inv)};
    *(float2*)&mean[(long long)r * CDIM + lane * 4] = *(float2*)hv;
}

// ---------------- fused per-node attention + mean pool (fp16 qkv) ----------
__global__ __launch_bounds__(256) void attn_pool_k(
    const __half* __restrict__ qkv, float* __restrict__ pooled, int nNodes)
{
    __shared__ float sh[4][3072];
    __shared__ float sW[4][16];
    const int tid = threadIdx.x;
    const int wid = tid >> 6, lane = tid & 63;
    const int node = blockIdx.x * 4 + wid;   // nNodes % 4 == 0: never OOB
    float* S = sh[wid];
    const __half* base = qkv + (long long)node * 3072;
    #pragma unroll
    for (int it = 0; it < 6; ++it) {
        int f = it * 64 + lane;              // 0..383
        f16x8 v = *(const f16x8*)&base[f * 8];
        #pragma unroll
        for (int e = 0; e < 8; ++e) S[f * 8 + e] = (float)v[e];
    }
    __syncthreads();
    const int h = lane >> 4, qm = (lane >> 2) & 3, km = lane & 3;
    const float* qrow = &S[qm * 768 + h * 64];
    const float* krow = &S[km * 768 + 256 + h * 64];
    float s = 0.0f;
    #pragma unroll
    for (int i = 0; i < 64; ++i) s = fmaf(qrow[i], krow[i], s);
    s *= 0.125f;  // 1/sqrt(64)
    float mx = fmaxf(s, __shfl_xor(s, 1));
    mx = fmaxf(mx, __shfl_xor(mx, 2));
    float e = __expf(s - mx);
    float sum = e + __shfl_xor(e, 1);
    sum += __shfl_xor(sum, 2);
    float a = e / sum;
    float tt = a + __shfl_xor(a, 4);
    tt += __shfl_xor(tt, 8);
    if (qm == 0) sW[wid][h * 4 + km] = 0.25f * tt;
    __syncthreads();
    #pragma unroll
    for (int j = 0; j < 4; ++j) {
        int c = j * 64 + lane;
        float p = 0.0f;
        #pragma unroll
        for (int kk = 0; kk < 4; ++kk)
            p = fmaf(sW[wid][j * 4 + kk], S[kk * 768 + 512 + c], p);
        pooled[(long long)node * 256 + c] = p;
    }
}

// ---------------- final: out[n] = h[n] . mlp2_w + mlp2_b -------------------
__global__ __launch_bounds__(256) void mlp2_k(
    const __half* __restrict__ h, const float* __restrict__ w,
    const float* __restrict__ b, float* __restrict__ out, int n)
{
    int t = blockIdx.x * 256 + threadIdx.x;
    int node = t >> 6, lane = t & 63;
    if (node >= n) return;
    const float4 hv = ld4(&h[(long long)node * CDIM + lane * 4]);
    const float4 wv = *(const float4*)&w[lane * 4];
    float s = hv.x * wv.x + hv.y * wv.y + hv.z * wv.z + hv.w * wv.w;
    #pragma unroll
    for (int off = 1; off < 64; off <<= 1) s += __shfl_xor(s, off);
    if (lane == 0) out[node] = s + b[0];
}

// ---------------- diagnostic fallback --------------------------------------
__global__ void diag_k(float* out, int n, float val)
{
    int t = blockIdx.x * 256 + threadIdx.x;
    if (t < n) out[t] = val;
}

// ---------------------------------------------------------------------------
extern "C" void kernel_launch(void* const* d_in, const int* in_sizes, int n_in,
                              void* d_out, int out_size, void* d_ws, size_t ws_size,
                              hipStream_t stream)
{
    const float* x_a  = (const float*)d_in[0];
    const float* x_b  = (const float*)d_in[1];
    const int*   e_ab = (const int*)d_in[2];
    const int*   e_ba = (const int*)d_in[3];
    const float* wl1  = (const float*)d_in[4];
    const float* wr1  = (const float*)d_in[5];
    const float* b1   = (const float*)d_in[6];
    const float* wl2  = (const float*)d_in[7];
    const float* wr2  = (const float*)d_in[8];
    const float* b2   = (const float*)d_in[9];
    const float* outw = (const float*)d_in[10];
    const float* outb = (const float*)d_in[11];
    const float* mpw  = (const float*)d_in[12];
    const float* ipw  = (const float*)d_in[13];  // [768,256]
    const float* ipb  = (const float*)d_in[14];  // [768]
    const float* aow  = (const float*)d_in[15];  // [256,256]
    const float* aob  = (const float*)d_in[16];
    const float* m1w  = (const float*)d_in[17];
    const float* m1b  = (const float*)d_in[18];
    const float* m2w  = (const float*)d_in[19];
    const float* m2b  = (const float*)d_in[20];
    float* out = (float*)d_out;

    // gate: NEED identical to rounds 4-8 (ws known >= this)
    const size_t NEED = 40960000ull + 82240000ull + 40960000ull + 81920000ull
                      + 786432ull + 262144ull;   // 247,128,576
    if (ws_size < NEED || n_in < 21 || out_size != N_A) {
        float diag = (float)((ws_size / (1024ull * 1024ull)) * 100ull + (size_t)n_in);
        diag_k<<<(out_size + 255) / 256, 256, 0, stream>>>(out, out_size, diag);
        return;
    }

    // ---- layout (bytes): XA16 | XB16 | WH | AREG | BREG | EMBS ----
    char* base = (char*)d_ws;
    __half* XA16 = (__half*)(base);                    // 20,480,000
    __half* XB16 = (__half*)(base + 20480000);         // 40,960,000
    __half* WH   = (__half*)(base + 61440000);         //  4,194,304
    char*   AREG = base + 65634304;                    // 40,960,000
    char*   BREG = base + 106594304;                   // 40,960,000
    __half* EMBS = (__half*)(base + 147554304);        // 81,920,000
    // WH sublayout (halves)
    __half* WL1T  = WH;                  // 4x[256][256]
    __half* WR1T  = WH + 262144;
    __half* BT2   = WH + 524288;         // 4x[256][512] (wr2|wl2)
    __half* OUTWT = WH + 1048576;
    __half* IPW16 = WH + 1310720;        // [768][256]
    __half* WCT   = WH + 1507328;        // [256][256]
    float*  BC    = (float*)(WH + 1572864);
    // rotating scratch
    __half* ZH     = (__half*)AREG;              // 20.48 MB
    __half* HBH    = (__half*)AREG;              // 40.96 MB (after CSR-B dead)
    __half* HA16   = (__half*)AREG;              // 20.48 MB
    __half* QKVC16 = (__half*)AREG;              // 24.58 MB (phase 2)
    __half* TMLP16 = (__half*)AREG;              // 20.48 MB (tail)
    __half* MEANB16 = (__half*)BREG;             // 40.96 MB
    __half* MEANA16 = (__half*)BREG;             // 20.48 MB
    float*  POOL    = (float*)BREG;              // 40.96 MB (phase 2)
    // CSR-B in AREG upper half (alive steps 2-3 only; ZH uses lower half)
    int* cntB   = (int*)(AREG + 20480000);
    int* startB = cntB + N_B;
    int* cursB  = cntB + 2 * N_B;
    int* eidxB  = cntB + 3 * N_B;
    int* bsumB  = eidxB + EDG;
    int* boffB  = bsumB + 512;
    // CSR-A in BREG upper half (alive steps 5-6; MEANA uses lower half)
    int* cntA   = (int*)(BREG + 20480000);
    int* startA = cntA + N_A;
    int* cursA  = cntA + 2 * N_A;
    int* eidxA  = cntA + 3 * N_A;
    int* bsumA  = eidxA + EDG;
    int* boffA  = bsumA + 512;

    // ---- one-time conversions ----
    cvt8_k<<<5000, 256, 0, stream>>>(x_a, XA16, 1280000);
    cvt8_k<<<10000, 256, 0, stream>>>(x_b, XB16, 2560000);
    cvt_tr_k<<<1024, 256, 0, stream>>>(wl1, WL1T, 4);
    cvt_tr_k<<<1024, 256, 0, stream>>>(wr1, WR1T, 4);
    cvt_tr_k<<<1024, 256, 0, stream>>>(outw, OUTWT, 4);
    cvt_bt2_k<<<2048, 256, 0, stream>>>(wr2, wl2, BT2);
    cvt_flat_k<<<768, 256, 0, stream>>>(ipw, IPW16, 196608);
    wc_k<<<256, 256, 0, stream>>>(aow, m1w, WCT);
    bc_k<<<1, 256, 0, stream>>>(aob, m1w, m1b, BC);

    const int EB = (EDG + 255) / 256;
    const int NBB = (N_B + 255) / 256;   // 313
    const int NBA = (N_A + 255) / 256;   // 157

    for (int m = 0; m < MP; ++m) {
        const int* sab = e_ab + (size_t)m * 2 * EDG;
        const int* dab = sab + EDG;
        const int* sba = e_ba + (size_t)m * 2 * EDG;
        const int* dba = sba + EDG;

        // z = x_a @ wl1[m] -> ZH (AREG lower)
        mgemm_k<__half, __half, float, false, false, false, false, false>
            <<<dim3(2, N_A / 64), 256, 0, stream>>>(
            XA16, CDIM, nullptr, WL1T + m * 65536, nullptr, nullptr, 0,
            nullptr, 0, ZH, CDIM, CDIM);
        // CSR-B (AREG upper)
        hipMemsetAsync(cntB, 0, (size_t)N_B * 4, stream);
        hist_k<<<EB, 256, 0, stream>>>(dab, cntB, EDG);
        scan_blk_k<<<NBB, 256, 0, stream>>>(cntB, bsumB, N_B);
        scan_top_k<<<1, 512, 0, stream>>>(bsumB, boffB, NBB);
        scan_fin_k<<<NBB, 256, 0, stream>>>(cntB, boffB, startB, cursB, N_B);
        fill_k<<<EB, 256, 0, stream>>>(sab, dab, cursB, eidxB, EDG);
        gather_mean_k<<<N_B / 4, 256, 0, stream>>>(
            ZH, startB, cntB, eidxB, MEANB16, N_B);
        // h_b = relu(x_b @ wr1[m] + b1 + mean_b) -> HBH (AREG full; CSR-B dead)
        mgemm_k<__half, __half, __half, false, true, true, true, false>
            <<<dim3(2, N_B / 64), 256, 0, stream>>>(
            XB16, CDIM, nullptr, WR1T + m * 65536, b1 + (size_t)m * CDIM,
            MEANB16, CDIM, nullptr, 0, HBH, CDIM, CDIM);
        // CSR-A (BREG upper; MEANB dead)
        hipMemsetAsync(cntA, 0, (size_t)N_A * 4, stream);
        hist_k<<<EB, 256, 0, stream>>>(dba, cntA, EDG);
        scan_blk_k<<<NBA, 256, 0, stream>>>(cntA, bsumA, N_A);
        scan_top_k<<<1, 512, 0, stream>>>(bsumA, boffA, NBA);
        scan_fin_k<<<NBA, 256, 0, stream>>>(cntA, boffA, startA, cursA, N_A);
        fill_k<<<EB, 256, 0, stream>>>(sba, dba, cursA, eidxA, EDG);
        gather_mean_k<<<N_A / 4, 256, 0, stream>>>(
            HBH, startA, cntA, eidxA, MEANA16, N_A);
        // h_a = relu([x_a | mean_a] @ [wr2;wl2]^T + b2)  (K=512 fused)
        mgemm_k<__half, __half, float, true, false, true, true, false>
            <<<dim3(2, N_A / 64), 256, 0, stream>>>(
            XA16, CDIM, MEANA16, BT2 + m * 131072, b2 + (size_t)m * CDIM,
            nullptr, 0, nullptr, 0, HA16, CDIM, 512);
        // embs[:,m,:] = (h_a @ outw[m] + outb[m]) * mpw[m]
        mgemm_k<__half, __half, float, false, false, true, false, true>
            <<<dim3(2, N_A / 64), 256, 0, stream>>>(
            HA16, CDIM, nullptr, OUTWT + m * 65536, outb + (size_t)m * CDIM,
            nullptr, 0, mpw, m, EMBS + (size_t)m * CDIM, 1024, CDIM);
    }

    // phase 2: chunked qkv (fp16) + fused attention/pool
    const int CH = 4000;  // 16000 rows/chunk
    for (int ch = 0; ch < N_A / CH; ++ch) {
        const int n0 = ch * CH;
        mgemm_k<__half, __half, float, false, false, true, false, false>
            <<<dim3(6, (CH * 4) / 64), 256, 0, stream>>>(
            EMBS + (size_t)n0 * 1024, CDIM, nullptr, IPW16, ipb, nullptr, 0,
            nullptr, 0, QKVC16, 768, CDIM);
        attn_pool_k<<<CH / 4, 256, 0, stream>>>(QKVC16, POOL + (size_t)n0 * 256, CH);
    }
    // tmlp = relu(pooled @ W_c + b_c)   (attn_out folded into mlp1)
    mgemm_k<float, __half, float, false, false, true, true, false>
        <<<dim3(2, N_A / 64), 256, 0, stream>>>(
        POOL, CDIM, nullptr, WCT, BC, nullptr, 0, nullptr, 0, TMLP16, CDIM, CDIM);
    mlp2_k<<<(N_A * 64) / 256, 256, 0, stream>>>(TMLP16, m2w, m2b, out, N_A);
}

// Round 10
// 1372.154 us; speedup vs baseline: 7.2706x; 1.1150x over previous
//
#include <hip/hip_runtime.h>
#include <hip/hip_bf16.h>
#include <hip/hip_fp16.h>

// ---------------------------------------------------------------------------
// MPSGNN: 4 metapath SAGE GNNs + metapath attention + MLP head.
// N_A=40000, N_B=80000, C=256, M=4, E=250000, heads=4 (d=64)
// Round 10: launch-count collapse (95 -> 43). Batched upfront CSR build for
// all 8 edge lists (6 launches), QKV chunks 10->4, weight-prep merged into
// one kernel, fp16 POOL. Math identical to round 9.
// ---------------------------------------------------------------------------

#define N_A 40000
#define N_B 80000
#define CDIM 256
#define MP 4
#define EDG 250000

using f16x8 = __attribute__((ext_vector_type(8))) _Float16;
using f32x4 = __attribute__((ext_vector_type(4))) float;

// ---- dtype helpers --------------------------------------------------------
__device__ __forceinline__ float ldf(const float* p) { return *p; }
__device__ __forceinline__ float ldf(const __half* p) { return __half2float(*p); }
__device__ __forceinline__ void stf(float* p, float v) { *p = v; }
__device__ __forceinline__ void stf(__half* p, float v) { *p = __float2half(v); }

__device__ __forceinline__ float4 ld4(const __half* p) {
    __half2 a = *(const __half2*)p, b = *(const __half2*)(p + 2);
    float2 fa = __half22float2(a), fb = __half22float2(b);
    return make_float4(fa.x, fa.y, fb.x, fb.y);
}

// ---------------- MFMA GEMM: C[M,N] = act(A[M,K] @ BT[N,K]^T + ...) --------
// Tile 64(M) x 128(N), BK=32, 256 threads = 4 waves (2x2), each wave 32x64.
// FUSE2: A is [x | A2] along K (both __half, lda/256), BT pre-concatenated.
template<typename AT, typename CT, typename ET, bool FUSE2, bool EXTRA,
         bool BIAS, bool RELU, bool OSCALE>
__global__ __launch_bounds__(256) void mgemm_k(
    const AT* __restrict__ A, int lda,
    const __half* __restrict__ A2,
    const __half* __restrict__ BT,
    const float* __restrict__ bias,
    const ET* __restrict__ extra, int lde,
    const float* __restrict__ osp, int osi,
    CT* __restrict__ C, int ldc, int K)
{
    __shared__ __align__(16) _Float16 As[64 * 40];   // [m][k], pad 40
    __shared__ __align__(16) _Float16 Bs[128 * 40];  // [n][k]
    const int tid = threadIdx.x;
    const int w = tid >> 6, lane = tid & 63;
    const int wm = w & 1, wn = w >> 1;
    const int lr = lane & 15, kb = lane >> 4;
    const long long row0 = (long long)blockIdx.y * 64;
    const int col0 = blockIdx.x * 128;
    f32x4 acc[2][4] = {};
    for (int k0 = 0; k0 < K; k0 += 32) {
        // stage A: 64 rows x 32 k (8 elems/thread)
        {
            int flat = tid * 8;
            int r = flat >> 5, c = flat & 31;
            int kk = k0 + c;
            if constexpr (FUSE2) {
                const __half* src = (kk < 256)
                    ? (const __half*)&A[(row0 + r) * lda + kk]
                    : &A2[(row0 + r) * 256 + (kk - 256)];
                *(f16x8*)&As[r * 40 + c] = *(const f16x8*)src;
            } else if constexpr (sizeof(AT) == 4) {
                const AT* src = &A[(row0 + r) * lda + kk];
                float4 v0 = *(const float4*)(src);
                float4 v1 = *(const float4*)(src + 4);
                _Float16 h[8] = {(_Float16)v0.x, (_Float16)v0.y, (_Float16)v0.z,
                                 (_Float16)v0.w, (_Float16)v1.x, (_Float16)v1.y,
                                 (_Float16)v1.z, (_Float16)v1.w};
                *(f16x8*)&As[r * 40 + c] = *(f16x8*)h;
            } else {
                *(f16x8*)&As[r * 40 + c] =
                    *(const f16x8*)&A[(row0 + r) * lda + kk];
            }
        }
        // stage B: 128 rows x 32 k from BT
        {
            #pragma unroll
            for (int q = 0; q < 2; ++q) {
                int cid = tid * 2 + q;
                int r = cid >> 2, cc = cid & 3;
                *(f16x8*)&Bs[r * 40 + cc * 8] =
                    *(const f16x8*)&BT[(long long)(col0 + r) * K + k0 + cc * 8];
            }
        }
        __syncthreads();
        f16x8 af[2], bf[4];
        #pragma unroll
        for (int i = 0; i < 2; ++i)
            af[i] = *(f16x8*)&As[(wm * 32 + i * 16 + lr) * 40 + kb * 8];
        #pragma unroll
        for (int j = 0; j < 4; ++j)
            bf[j] = *(f16x8*)&Bs[(wn * 64 + j * 16 + lr) * 40 + kb * 8];
        #pragma unroll
        for (int i = 0; i < 2; ++i)
            #pragma unroll
            for (int j = 0; j < 4; ++j)
                acc[i][j] = __builtin_amdgcn_mfma_f32_16x16x32_f16(
                    af[i], bf[j], acc[i][j], 0, 0, 0);
        __syncthreads();
    }
    float osc = 1.0f;
    if (OSCALE) osc = osp[osi];
    #pragma unroll
    for (int i = 0; i < 2; ++i) {
        #pragma unroll
        for (int j = 0; j < 4; ++j) {
            #pragma unroll
            for (int r = 0; r < 4; ++r) {
                long long rg = row0 + wm * 32 + i * 16 + (lane >> 4) * 4 + r;
                int cg = col0 + wn * 64 + j * 16 + (lane & 15);
                float v = acc[i][j][r];
                if (EXTRA) v += ldf(&extra[rg * lde + cg]);
                if (BIAS) v += bias[cg];
                if (RELU) v = fmaxf(v, 0.0f);
                if (OSCALE) v *= osc;
                stf(&C[rg * ldc + cg], v);
            }
        }
    }
}

// ---------------- input fp32 -> fp16 ---------------------------------------
__global__ void cvt8_k(const float* __restrict__ s, __half* __restrict__ d, int n8)
{
    int t = blockIdx.x * 256 + threadIdx.x;
    if (t >= n8) return;
    const float4 a = *(const float4*)&s[t * 8];
    const float4 b = *(const float4*)&s[t * 8 + 4];
    _Float16 h[8] = {(_Float16)a.x, (_Float16)a.y, (_Float16)a.z, (_Float16)a.w,
                     (_Float16)b.x, (_Float16)b.y, (_Float16)b.z, (_Float16)b.w};
    *(f16x8*)&d[t * 8] = *(f16x8*)h;
}

// ---------------- merged weight prep (7 sections via blockIdx.y) -----------
__global__ __launch_bounds__(256) void prep_k(
    const float* __restrict__ wl1, const float* __restrict__ wr1,
    const float* __restrict__ outw, const float* __restrict__ wr2,
    const float* __restrict__ wl2, const float* __restrict__ ipw,
    const float* __restrict__ aow, const float* __restrict__ m1w,
    const float* __restrict__ aob, const float* __restrict__ m1b,
    __half* __restrict__ WL1T, __half* __restrict__ WR1T,
    __half* __restrict__ OUTWT, __half* __restrict__ BT2,
    __half* __restrict__ IPW16, __half* __restrict__ WCT,
    float* __restrict__ BC)
{
    const int sec = blockIdx.y;
    const int t = blockIdx.x * 256 + threadIdx.x;
    if (sec < 3) {            // transposes: 4x[256][256], d[m][c][r]=s[m][r][c]
        if (t >= 262144) return;
        const float* s = (sec == 0) ? wl1 : (sec == 1) ? wr1 : outw;
        __half* d = (sec == 0) ? WL1T : (sec == 1) ? WR1T : OUTWT;
        int m = t >> 16, i = t & 65535, r = i >> 8, c = i & 255;
        d[(m << 16) + (c << 8) + r] = __float2half(s[t]);
    } else if (sec == 3) {    // BT2[m][n][k]: wr2 | wl2 transposed concat
        if (t >= 524288) return;
        int m = t >> 17, i = t & 131071, n = i >> 9, k = i & 511;
        float v = (k < 256) ? wr2[(m << 16) + (k << 8) + n]
                            : wl2[(m << 16) + ((k - 256) << 8) + n];
        BT2[t] = __float2half(v);
    } else if (sec == 4) {    // ipw flat copy-cast
        if (t >= 196608) return;
        IPW16[t] = __float2half(ipw[t]);
    } else if (sec == 5) {    // WcT[n][k] = sum_j aow[j][k]*m1w[j][n]
        if (t >= 65536) return;
        int n = t >> 8, k = t & 255;
        float s = 0.0f;
        for (int j = 0; j < 256; ++j)
            s = fmaf(aow[j * 256 + k], m1w[j * 256 + n], s);
        WCT[t] = __float2half(s);
    } else {                  // bc[n] = aob . m1w[:,n] + m1b[n]
        if (t >= 256) return;
        float s = m1b[t];
        for (int j = 0; j < 256; ++j) s = fmaf(aob[j], m1w[j * 256 + t], s);
        BC[t] = s;
    }
}

// ---------------- batched CSR build over 8 lists (blockIdx.y = list) -------
// list l: m = l>>1; dir = l&1 (0: ab edges, dst in B; 1: ba edges, dst in A).
// Uniform n=80000 per list (A-lists' tail counts stay 0 from memset).
__global__ __launch_bounds__(256) void hist_all_k(
    const int* __restrict__ e_ab, const int* __restrict__ e_ba,
    int* __restrict__ cnt_all)
{
    const int l = blockIdx.y;
    const int e = blockIdx.x * 256 + threadIdx.x;
    if (e >= EDG) return;
    const int m = l >> 1, dir = l & 1;
    const int* dst = (dir ? e_ba : e_ab) + (size_t)m * 2 * EDG + EDG;
    atomicAdd(&cnt_all[l * 80000 + dst[e]], 1);
}
__global__ __launch_bounds__(256) void scan_blk_all_k(
    const int* __restrict__ cnt_all, int* __restrict__ bsum_all)
{
    __shared__ int s[256];
    const int l = blockIdx.y, t = threadIdx.x;
    const int i = blockIdx.x * 256 + t;
    s[t] = (i < 80000) ? cnt_all[l * 80000 + i] : 0;
    __syncthreads();
    for (int off = 128; off > 0; off >>= 1) {
        if (t < off) s[t] += s[t + off];
        __syncthreads();
    }
    if (t == 0) bsum_all[l * 313 + blockIdx.x] = s[0];
}
__global__ __launch_bounds__(512) void scan_top_all_k(
    const int* __restrict__ bsum_all, int* __restrict__ boff_all)
{
    __shared__ int s[512];
    const int l = blockIdx.x, t = threadIdx.x;
    int v = (t < 313) ? bsum_all[l * 313 + t] : 0;
    s[t] = v;
    __syncthreads();
    for (int off = 1; off < 512; off <<= 1) {
        int u = (t >= off) ? s[t - off] : 0;
        __syncthreads();
        s[t] += u;
        __syncthreads();
    }
    if (t < 313) boff_all[l * 313 + t] = s[t] - v;  // exclusive
}
__global__ __launch_bounds__(256) void scan_fin_all_k(
    const int* __restrict__ cnt_all, const int* __restrict__ boff_all,
    int* __restrict__ start_all, int* __restrict__ cursor_all)
{
    __shared__ int s[256];
    const int l = blockIdx.y, t = threadIdx.x;
    const int i = blockIdx.x * 256 + t;
    int v = (i < 80000) ? cnt_all[l * 80000 + i] : 0;
    s[t] = v;
    __syncthreads();
    for (int off = 1; off < 256; off <<= 1) {
        int u = (t >= off) ? s[t - off] : 0;
        __syncthreads();
        s[t] += u;
        __syncthreads();
    }
    if (i < 80000) {
        int ex = boff_all[l * 313 + blockIdx.x] + s[t] - v;
        start_all[l * 80000 + i] = ex;
        cursor_all[l * 80000 + i] = ex;
    }
}
__global__ __launch_bounds__(256) void fill_all_k(
    const int* __restrict__ e_ab, const int* __restrict__ e_ba,
    int* __restrict__ cursor_all, int* __restrict__ eidx_all)
{
    const int l = blockIdx.y;
    const int e = blockIdx.x * 256 + threadIdx.x;
    if (e >= EDG) return;
    const int m = l >> 1, dir = l & 1;
    const int* src = (dir ? e_ba : e_ab) + (size_t)m * 2 * EDG;
    const int* dst = src + EDG;
    int p = atomicAdd(&cursor_all[l * 80000 + dst[e]], 1);
    eidx_all[l * 250000 + p] = src[e];
}

// ---------------- gather-mean (fp16 in, fp16 out) --------------------------
__global__ __launch_bounds__(256) void gather_mean_k(
    const __half* __restrict__ feat, const int* __restrict__ start,
    const int* __restrict__ cnt, const int* __restrict__ eidx,
    __half* __restrict__ mean, int n)
{
    int t = blockIdx.x * 256 + threadIdx.x;
    int r = t >> 6, lane = t & 63;
    if (r >= n) return;
    const int s0 = start[r], deg = cnt[r];
    float4 acc = make_float4(0.f, 0.f, 0.f, 0.f);
    for (int i = 0; i < deg; ++i) {
        int s = eidx[s0 + i];
        float4 v = ld4(&feat[(long long)s * CDIM + lane * 4]);
        acc.x += v.x; acc.y += v.y; acc.z += v.z; acc.w += v.w;
    }
    const float inv = 1.0f / fmaxf((float)deg, 1.0f);
    __half hv[4] = {__float2half(acc.x * inv), __float2half(acc.y * inv),
                    __float2half(acc.z * inv), __float2half(acc.w * inv)};
    *(float2*)&mean[(long long)r * CDIM + lane * 4] = *(float2*)hv;
}

// ---------------- fused per-node attention + mean pool (fp16 in/out) -------
__global__ __launch_bounds__(256) void attn_pool_k(
    const __half* __restrict__ qkv, __half* __restrict__ pooled, int nNodes)
{
    __shared__ float sh[4][3072];
    __shared__ float sW[4][16];
    const int tid = threadIdx.x;
    const int wid = tid >> 6, lane = tid & 63;
    const int node = blockIdx.x * 4 + wid;   // nNodes % 4 == 0: never OOB
    float* S = sh[wid];
    const __half* base = qkv + (long long)node * 3072;
    #pragma unroll
    for (int it = 0; it < 6; ++it) {
        int f = it * 64 + lane;              // 0..383
        f16x8 v = *(const f16x8*)&base[f * 8];
        #pragma unroll
        for (int e = 0; e < 8; ++e) S[f * 8 + e] = (float)v[e];
    }
    __syncthreads();
    const int h = lane >> 4, qm = (lane >> 2) & 3, km = lane & 3;
    const float* qrow = &S[qm * 768 + h * 64];
    const float* krow = &S[km * 768 + 256 + h * 64];
    float s = 0.0f;
    #pragma unroll
    for (int i = 0; i < 64; ++i) s = fmaf(qrow[i], krow[i], s);
    s *= 0.125f;  // 1/sqrt(64)
    float mx = fmaxf(s, __shfl_xor(s, 1));
    mx = fmaxf(mx, __shfl_xor(mx, 2));
    float e = __expf(s - mx);
    float sum = e + __shfl_xor(e, 1);
    sum += __shfl_xor(sum, 2);
    float a = e / sum;
    float tt = a + __shfl_xor(a, 4);
    tt += __shfl_xor(tt, 8);
    if (qm == 0) sW[wid][h * 4 + km] = 0.25f * tt;
    __syncthreads();
    #pragma unroll
    for (int j = 0; j < 4; ++j) {
        int c = j * 64 + lane;
        float p = 0.0f;
        #pragma unroll
        for (int kk = 0; kk < 4; ++kk)
            p = fmaf(sW[wid][j * 4 + kk], S[kk * 768 + 512 + c], p);
        pooled[(long long)node * 256 + c] = __float2half(p);
    }
}

// ---------------- final: out[n] = h[n] . mlp2_w + mlp2_b -------------------
__global__ __launch_bounds__(256) void mlp2_k(
    const __half* __restrict__ h, const float* __restrict__ w,
    const float* __restrict__ b, float* __restrict__ out, int n)
{
    int t = blockIdx.x * 256 + threadIdx.x;
    int node = t >> 6, lane = t & 63;
    if (node >= n) return;
    const float4 hv = ld4(&h[(long long)node * CDIM + lane * 4]);
    const float4 wv = *(const float4*)&w[lane * 4];
    float s = hv.x * wv.x + hv.y * wv.y + hv.z * wv.z + hv.w * wv.w;
    #pragma unroll
    for (int off = 1; off < 64; off <<= 1) s += __shfl_xor(s, off);
    if (lane == 0) out[node] = s + b[0];
}

// ---------------- diagnostic fallback --------------------------------------
__global__ void diag_k(float* out, int n, float val)
{
    int t = blockIdx.x * 256 + threadIdx.x;
    if (t < n) out[t] = val;
}

// ---------------------------------------------------------------------------
extern "C" void kernel_launch(void* const* d_in, const int* in_sizes, int n_in,
                              void* d_out, int out_size, void* d_ws, size_t ws_size,
                              hipStream_t stream)
{
    const float* x_a  = (const float*)d_in[0];
    const float* x_b  = (const float*)d_in[1];
    const int*   e_ab = (const int*)d_in[2];
    const int*   e_ba = (const int*)d_in[3];
    const float* wl1  = (const float*)d_in[4];
    const float* wr1  = (const float*)d_in[5];
    const float* b1   = (const float*)d_in[6];
    const float* wl2  = (const float*)d_in[7];
    const float* wr2  = (const float*)d_in[8];
    const float* b2   = (const float*)d_in[9];
    const float* outw = (const float*)d_in[10];
    const float* outb = (const float*)d_in[11];
    const float* mpw  = (const float*)d_in[12];
    const float* ipw  = (const float*)d_in[13];  // [768,256]
    const float* ipb  = (const float*)d_in[14];  // [768]
    const float* aow  = (const float*)d_in[15];  // [256,256]
    const float* aob  = (const float*)d_in[16];
    const float* m1w  = (const float*)d_in[17];
    const float* m1b  = (const float*)d_in[18];
    const float* m2w  = (const float*)d_in[19];
    const float* m2b  = (const float*)d_in[20];
    float* out = (float*)d_out;

    // gate: NEED identical to rounds 4-9
    const size_t NEED = 40960000ull + 82240000ull + 40960000ull + 81920000ull
                      + 786432ull + 262144ull;   // 247,128,576
    if (ws_size < NEED || n_in < 21 || out_size != N_A) {
        float diag = (float)((ws_size / (1024ull * 1024ull)) * 100ull + (size_t)n_in);
        diag_k<<<(out_size + 255) / 256, 256, 0, stream>>>(out, out_size, diag);
        return;
    }

    // ---- layout (bytes): XA16 | XB16 | WH | AREG | BREG | EMBS | CSRALL ----
    char* base = (char*)d_ws;
    __half* XA16 = (__half*)(base);                    // 20,480,000
    __half* XB16 = (__half*)(base + 20480000);         // 40,960,000
    __half* WH   = (__half*)(base + 61440000);         //  4,194,304
    char*   AREG = base + 65634304;                    // 40,960,000
    char*   BREG = base + 106594304;                   // 40,960,000 (contig w/ AREG)
    __half* EMBS = (__half*)(base + 147554304);        // 81,920,000
    int*    CSR  = (int*)(base + 229474304);           // 15,700,032 (ends 245.2MB)
    // WH sublayout (halves)
    __half* WL1T  = WH;                  // 4x[256][256]
    __half* WR1T  = WH + 262144;
    __half* BT2   = WH + 524288;         // 4x[256][512] (wr2|wl2)
    __half* OUTWT = WH + 1048576;
    __half* IPW16 = WH + 1310720;        // [768][256]
    __half* WCT   = WH + 1507328;        // [256][256]
    float*  BC    = (float*)(WH + 1572864);
    // CSRALL sublayout (ints, uniform 80k stride per list, 8 lists)
    int* cnt_all    = CSR;               // 640,000
    int* start_all  = CSR + 640000;      // 640,000
    int* cursor_all = CSR + 1280000;     // 640,000
    int* eidx_all   = CSR + 1920000;     // 2,000,000
    int* bsum_all   = CSR + 3920000;     // 2,504
    int* boff_all   = CSR + 3922504;     // 2,504
    // rotating scratch (phase 1)
    __half* ZH      = (__half*)AREG;     // 20.48 MB
    __half* HBH     = (__half*)AREG;     // 40.96 MB (over ZH; ZH dead)
    __half* MEANB16 = (__half*)BREG;     // 40.96 MB
    __half* MEANA16 = (__half*)BREG;     // 20.48 MB (over MEANB; dead)
    __half* HA16    = (__half*)(BREG + 20480000);  // 20.48 MB
    // phase 2 overlays (AREG+BREG = contiguous 81.92 MB)
    __half* QKV16   = (__half*)AREG;               // 61.44 MB (CH=10000 chunk)
    __half* POOL16  = (__half*)(AREG + 61440000);  // 20.48 MB
    __half* TMLP16  = (__half*)AREG;               // 20.48 MB (QKV dead)

    // ---- conversions + weight prep (3 launches) ----
    cvt8_k<<<5000, 256, 0, stream>>>(x_a, XA16, 1280000);
    cvt8_k<<<10000, 256, 0, stream>>>(x_b, XB16, 2560000);
    prep_k<<<dim3(2048, 7), 256, 0, stream>>>(
        wl1, wr1, outw, wr2, wl2, ipw, aow, m1w, aob, m1b,
        WL1T, WR1T, OUTWT, BT2, IPW16, WCT, BC);

    // ---- batched CSR build for all 8 lists (6 launches) ----
    const int EB = (EDG + 255) / 256;    // 977
    hipMemsetAsync(cnt_all, 0, 640000 * 4, stream);
    hist_all_k<<<dim3(EB, 8), 256, 0, stream>>>(e_ab, e_ba, cnt_all);
    scan_blk_all_k<<<dim3(313, 8), 256, 0, stream>>>(cnt_all, bsum_all);
    scan_top_all_k<<<8, 512, 0, stream>>>(bsum_all, boff_all);
    scan_fin_all_k<<<dim3(313, 8), 256, 0, stream>>>(cnt_all, boff_all,
                                                     start_all, cursor_all);
    fill_all_k<<<dim3(EB, 8), 256, 0, stream>>>(e_ab, e_ba, cursor_all, eidx_all);

    // ---- metapath loop (6 launches per m) ----
    for (int m = 0; m < MP; ++m) {
        const int lB = 2 * m, lA = 2 * m + 1;
        // z = x_a @ wl1[m] -> ZH
        mgemm_k<__half, __half, float, false, false, false, false, false>
            <<<dim3(2, N_A / 64), 256, 0, stream>>>(
            XA16, CDIM, nullptr, WL1T + m * 65536, nullptr, nullptr, 0,
            nullptr, 0, ZH, CDIM, CDIM);
        // mean_b = gather-mean of z rows (CSR list lB)
        gather_mean_k<<<N_B / 4, 256, 0, stream>>>(
            ZH, start_all + lB * 80000, cnt_all + lB * 80000,
            eidx_all + lB * 250000, MEANB16, N_B);
        // h_b = relu(x_b @ wr1[m] + b1 + mean_b) -> HBH (over ZH; ZH dead)
        mgemm_k<__half, __half, __half, false, true, true, true, false>
            <<<dim3(2, N_B / 64), 256, 0, stream>>>(
            XB16, CDIM, nullptr, WR1T + m * 65536, b1 + (size_t)m * CDIM,
            MEANB16, CDIM, nullptr, 0, HBH, CDIM, CDIM);
        // mean_a = gather-mean of h_b rows (CSR list lA; over MEANB, dead)
        gather_mean_k<<<N_A / 4, 256, 0, stream>>>(
            HBH, start_all + lA * 80000, cnt_all + lA * 80000,
            eidx_all + lA * 250000, MEANA16, N_A);
        // h_a = relu([x_a | mean_a] @ [wr2;wl2]^T + b2)  (K=512 fused)
        mgemm_k<__half, __half, float, true, false, true, true, false>
            <<<dim3(2, N_A / 64), 256, 0, stream>>>(
            XA16, CDIM, MEANA16, BT2 + m * 131072, b2 + (size_t)m * CDIM,
            nullptr, 0, nullptr, 0, HA16, CDIM, 512);
        // embs[:,m,:] = (h_a @ outw[m] + outb[m]) * mpw[m]
        mgemm_k<__half, __half, float, false, false, true, false, true>
            <<<dim3(2, N_A / 64), 256, 0, stream>>>(
            HA16, CDIM, nullptr, OUTWT + m * 65536, outb + (size_t)m * CDIM,
            nullptr, 0, mpw, m, EMBS + (size_t)m * CDIM, 1024, CDIM);
    }

    // ---- phase 2: qkv (4 chunks of CH=10000) + fused attention/pool ----
    const int CH = 10000;
    for (int ch = 0; ch < N_A / CH; ++ch) {
        const int n0 = ch * CH;
        mgemm_k<__half, __half, float, false, false, true, false, false>
            <<<dim3(6, (CH * 4) / 64), 256, 0, stream>>>(
            EMBS + (size_t)n0 * 1024, CDIM, nullptr, IPW16, ipb, nullptr, 0,
            nullptr, 0, QKV16, 768, CDIM);
        attn_pool_k<<<CH / 4, 256, 0, stream>>>(
            QKV16, POOL16 + (size_t)n0 * 256, CH);
    }
    // tmlp = relu(pooled @ W_c + b_c)   (attn_out folded into mlp1)
    mgemm_k<__half, __half, float, false, false, true, true, false>
        <<<dim3(2, N_A / 64), 256, 0, stream>>>(
        POOL16, CDIM, nullptr, WCT, BC, nullptr, 0, nullptr, 0,
        TMLP16, CDIM, CDIM);
    mlp2_k<<<(N_A * 64) / 256, 256, 0, stream>>>(TMLP16, m2w, m2b, out, N_A);
}